// Round 4
// baseline (6800.716 us; speedup 1.0000x reference)
//
#include <hip/hip_runtime.h>

#define B_  128
#define S_  256
#define E_  300
#define EP_ 320
#define H_  512
#define G_  2048   // 4*H
#define D1_ 1024   // 2*H
#define NP_ (B_*H_/2)   // u64 slots per parity buffer (2 f16 + tag each)

typedef _Float16 f16;
typedef __attribute__((ext_vector_type(8))) _Float16 f16x8;
typedef __attribute__((ext_vector_type(4))) float    f32x4;
typedef unsigned long long u64;
typedef unsigned int u32;

__device__ __forceinline__ float sigf(float x){ return 1.f/(1.f + __expf(-x)); }
__device__ __forceinline__ float tanhf_(float x){
  float e = __expf(-2.f*fabsf(x));
  float t = (1.f - e)/(1.f + e);
  return x < 0.f ? -t : t;
}

// Relaxed agent-scope atomics: route to the coherence point, bypassing the
// non-coherent per-XCD L2s. Round-2 lesson: the barrier/flag handshake cost
// ~4 serialized IF$ round-trips per step; h is now published as self-
// validating tagged u64s (tag = step+1 in high 32b, 2 f16 in low 32b) so the
// only cross-CU hop per step is the data itself.
__device__ __forceinline__ u64 aload64(const u64* p){
  return __hip_atomic_load((u64*)p, __ATOMIC_RELAXED, __HIP_MEMORY_SCOPE_AGENT);
}
__device__ __forceinline__ void astore64(u64* p, u64 v){
  __hip_atomic_store(p, v, __ATOMIC_RELAXED, __HIP_MEMORY_SCOPE_AGENT);
}
union H16 { u32 w[4]; f16x8 v; };
union FU { f16 f; unsigned short s; };

// ---------------- setup kernels ----------------

__global__ void k_f32_to_f16(const float* __restrict__ s, f16* __restrict__ d, int n){
  int i = blockIdx.x*blockDim.x + threadIdx.x;
  if (i < n) d[i] = (f16)s[i];
}

__global__ void k_pad_w(const float* __restrict__ s, f16* __restrict__ d, int rows, int ks, int kd){
  int i = blockIdx.x*blockDim.x + threadIdx.x;
  if (i >= rows*kd) return;
  int r = i/kd, k = i - r*kd;
  d[i] = (k < ks) ? (f16)s[(size_t)r*ks + k] : (f16)0.f;
}

__global__ void k_bias(const float* __restrict__ a, const float* __restrict__ b,
                       float* __restrict__ d, int n){
  int i = blockIdx.x*blockDim.x + threadIdx.x;
  if (i < n) d[i] = a[i] + b[i];
}

__global__ void k_len(const float* __restrict__ x, int* __restrict__ len){
  int b = threadIdx.x;
  if (b < B_){
    int v = (int)x[((size_t)b*S_ + (S_-1))*E_];
    len[b] = v > S_ ? S_ : v;
  }
}

// Tagged parity buffers: par0 = h_{-1}=1.0 with tag 0 (step-0 readers expect
// tag 0); par1 = sentinel tag that matches no step.
__global__ void k_init(u64* hxT, u64* hx1T, float* cstate){
  int i = blockIdx.x*blockDim.x + threadIdx.x;
  const u64 one2 = 0x3C003C00ull;               // tag 0 | f16(1),f16(1)
  const u64 sent = 0xFFFFFFFF00000000ull;       // never-matching tag
  if (i < NP_){
    hxT[i] = one2;              // dir0 par0
    hxT[NP_ + i] = sent;        // dir0 par1
    hxT[2*NP_ + i] = one2;      // dir1 par0
    hxT[3*NP_ + i] = sent;      // dir1 par1
    hx1T[i] = one2;
    hx1T[NP_ + i] = sent;
  }
  if (i < B_*H_) cstate[i] = 1.f;
}

// ---------------- GEMM: C[M,N] = A[M,K] @ B[N,K]^T + bias (f16 in/out, fp32 acc) ----------------

__global__ __launch_bounds__(256) void k_gemm_bt(
    const f16* __restrict__ A, const f16* __restrict__ Bm,
    f16* __restrict__ C, const float* __restrict__ bias,
    int M, int N, int K)
{
  __shared__ f16 As[64*40];
  __shared__ f16 Bs[64*40];
  const int m0 = blockIdx.x*64, n0 = blockIdx.y*64;
  const int tid = threadIdx.x;
  const int w = tid>>6, lane = tid&63, quad = lane>>4, l16 = lane&15;
  const int wm = (w&1)*32, wn = (w>>1)*32;
  const int lr = tid>>2, lc = (tid&3)*8;
  const f16* Ap = A + (size_t)(m0+lr)*K + lc;
  const f16* Bp = Bm + (size_t)(n0+lr)*K + lc;
  f32x4 z4 = {0.f,0.f,0.f,0.f};
  f32x4 acc[2][2] = {{z4,z4},{z4,z4}};
  for (int k0 = 0; k0 < K; k0 += 32){
    *(uint4*)&As[lr*40+lc] = *(const uint4*)(Ap + k0);
    *(uint4*)&Bs[lr*40+lc] = *(const uint4*)(Bp + k0);
    __syncthreads();
    f16x8 a0 = *(const f16x8*)&As[(wm+l16)*40 + quad*8];
    f16x8 a1 = *(const f16x8*)&As[(wm+16+l16)*40 + quad*8];
    f16x8 b0 = *(const f16x8*)&Bs[(wn+l16)*40 + quad*8];
    f16x8 b1 = *(const f16x8*)&Bs[(wn+16+l16)*40 + quad*8];
    acc[0][0] = __builtin_amdgcn_mfma_f32_16x16x32_f16(a0,b0,acc[0][0],0,0,0);
    acc[0][1] = __builtin_amdgcn_mfma_f32_16x16x32_f16(a0,b1,acc[0][1],0,0,0);
    acc[1][0] = __builtin_amdgcn_mfma_f32_16x16x32_f16(a1,b0,acc[1][0],0,0,0);
    acc[1][1] = __builtin_amdgcn_mfma_f32_16x16x32_f16(a1,b1,acc[1][1],0,0,0);
    __syncthreads();
  }
#pragma unroll
  for (int mi = 0; mi < 2; ++mi)
#pragma unroll
    for (int ni = 0; ni < 2; ++ni){
      int col = n0 + wn + ni*16 + l16;
      float bz = bias[col];
#pragma unroll
      for (int r = 0; r < 4; ++r){
        int row = m0 + wm + mi*16 + quad*4 + r;
        C[(size_t)row*N + col] = (f16)(acc[mi][ni][r] + bz);
      }
    }
}

// ---------------- phase A: persistent layer-0 fwd+rev, column-partitioned ----------------
// grid (2,32,2) = 128 blocks, 256 thr. Block: 64 batch rows x 16 hidden x 4 gates.
// Sync: NONE except the tagged h data itself. Each (dir,half,wave) row-group of
// 32 waves is an independent chain: wave publishes its 16x16 h tile as tagged
// u64s (tag = s+1); consumers retry-load until all tags match s. Parity
// double-buffer reuse is safe transitively: advancing 2 steps requires having
// observed tags from all same-row-group waves, which implies they consumed the
// buffer being overwritten.

__global__ __launch_bounds__(256, 1) void k_phaseA(
    const float* __restrict__ x,
    const f16* __restrict__ w0f, const f16* __restrict__ w0r,
    const f16* __restrict__ whf, const f16* __restrict__ whr,
    const float* __restrict__ bs0, const int* __restrict__ len,
    u64* __restrict__ hxT, f16* __restrict__ outcat)
{
  __shared__ f16 Wh[64*512];   // exactly 64 KB
  const int half = blockIdx.x, jb = blockIdx.y, dir = blockIdx.z;
  const f16* wih = dir ? w0r : w0f;
  const f16* whh = dir ? whr : whf;
  const float* bias = bs0 + dir*G_;
  u64* hx = hxT + (size_t)dir*(2*NP_);
  const int tid = threadIdx.x;
  const int w = tid>>6, lane = tid&63, quad = lane>>4, l16 = lane&15;
  const int j0 = jb*16;
  const int m0 = half*64 + w*16;       // this wave's 16 batch rows

  for (int u = tid; u < 4096; u += 256){
    int lrr = u>>6, uc = u&63;
    int g = lrr>>4, i = lrr&15;
    *(uint4*)&Wh[lrr*512 + (uc ^ (i&7))*8] =
        *(const uint4*)(whh + ((size_t)(g*H_ + j0 + i))*H_ + uc*8);
  }
  __syncthreads();

  const int j = j0 + l16;
  const f16* wiB[4];
#pragma unroll
  for (int g = 0; g < 4; ++g) wiB[g] = wih + (size_t)(g*H_ + j)*EP_ + quad*8;
  float bz[4], hprev[4], cpr[4]; int lm[4];
#pragma unroll
  for (int g = 0; g < 4; ++g) bz[g] = bias[g*H_ + j];
#pragma unroll
  for (int r = 0; r < 4; ++r){ hprev[r] = 1.f; cpr[r] = 1.f; lm[r] = len[m0 + quad*4 + r]; }
  const size_t xrowbase = (size_t)(m0 + l16)*S_;

  for (int s = 0; s < S_; ++s){
    const int t = dir ? (S_-1-s) : s;
    f32x4 z4 = {0.f,0.f,0.f,0.f};
    f32x4 acc[4] = {z4,z4,z4,z4};

    // --- x_t @ Wih^T (h-independent; overlaps producer publish latency) ---
    const float* xr = x + (xrowbase + t)*E_;
#pragma unroll
    for (int kb = 0; kb < 9; ++kb){
      float4 f0 = *(const float4*)(xr + kb*32 + quad*8);
      float4 f1 = *(const float4*)(xr + kb*32 + quad*8 + 4);
      f16x8 a;
      a[0]=(f16)f0.x; a[1]=(f16)f0.y; a[2]=(f16)f0.z; a[3]=(f16)f0.w;
      a[4]=(f16)f1.x; a[5]=(f16)f1.y; a[6]=(f16)f1.z; a[7]=(f16)f1.w;
#pragma unroll
      for (int g = 0; g < 4; ++g)
        acc[g] = __builtin_amdgcn_mfma_f32_16x16x32_f16(a, *(const f16x8*)(wiB[g] + kb*32), acc[g],0,0,0);
    }
    { // K tail 288..319 (x valid to 299; weight pad cols are zero)
      int kbase = 288 + quad*8;
      f16x8 a;
#pragma unroll
      for (int e2 = 0; e2 < 8; ++e2)
        a[e2] = (kbase + e2 < E_) ? (f16)xr[kbase + e2] : (f16)0.f;
#pragma unroll
      for (int g = 0; g < 4; ++g)
        acc[g] = __builtin_amdgcn_mfma_f32_16x16x32_f16(a, *(const f16x8*)(wiB[g] + 288), acc[g],0,0,0);
    }

    // --- h @ Whh^T (K=512); tagged A from coherence point, B from LDS.
    //     4 chunks of 4 K-blocks; prefetch next chunk before verifying current
    //     so all load latency overlaps; retry only on tag mismatch. ---
    const int par = s & 1;
    const u32 exp = (u32)s;
    const u64* hrow = hx + (size_t)par*NP_ + (size_t)(m0 + l16)*(H_/2);
    u64 q[2][16];
#pragma unroll
    for (int kk = 0; kk < 4; ++kk)
#pragma unroll
      for (int e = 0; e < 4; ++e)
        q[0][kk*4+e] = aload64(hrow + kk*16 + quad*4 + e);
#pragma unroll
    for (int c = 0; c < 4; ++c){
      if (c < 3){
#pragma unroll
        for (int kk = 0; kk < 4; ++kk)
#pragma unroll
          for (int e = 0; e < 4; ++e)
            q[(c+1)&1][kk*4+e] = aload64(hrow + (c+1)*64 + kk*16 + quad*4 + e);
      }
      for (;;){
        bool ok = true;
#pragma unroll
        for (int i2 = 0; i2 < 16; ++i2) ok &= ((u32)(q[c&1][i2]>>32) == exp);
        if (ok) break;
#pragma unroll
        for (int kk = 0; kk < 4; ++kk)
#pragma unroll
          for (int e = 0; e < 4; ++e)
            q[c&1][kk*4+e] = aload64(hrow + c*64 + kk*16 + quad*4 + e);
      }
#pragma unroll
      for (int kk = 0; kk < 4; ++kk){
        H16 ha;
#pragma unroll
        for (int e = 0; e < 4; ++e) ha.w[e] = (u32)q[c&1][kk*4+e];
        int uq = (c*4+kk)*4 + quad;
#pragma unroll
        for (int g = 0; g < 4; ++g){
          f16x8 b = *(const f16x8*)&Wh[(g*16+l16)*512 + ((uq ^ (l16&7)))*8];
          acc[g] = __builtin_amdgcn_mfma_f32_16x16x32_f16(ha.v, b, acc[g],0,0,0);
        }
      }
    }

    // --- gates + state update; publish tagged h (fire-and-forget) ---
    u64* hn = hx + (size_t)(1-par)*NP_;
    const u32 otag = (u32)(s+1);
#pragma unroll
    for (int r = 0; r < 4; ++r){
      int m = m0 + quad*4 + r;
      float zi = acc[0][r] + bz[0];
      float zf = acc[1][r] + bz[1];
      float zg = acc[2][r] + bz[2];
      float zo = acc[3][r] + bz[3];
      float ig = sigf(zi), fg = sigf(zf), gg = tanhf_(zg), og = sigf(zo);
      float cnew = fg*cpr[r] + ig*gg;
      float hnew = og*tanhf_(cnew);
      bool mk = t < lm[r];
      float hsel = mk ? hnew : hprev[r];
      cpr[r] = mk ? cnew : cpr[r];
      hprev[r] = hsel;
      FU cv; cv.f = (f16)hsel;
      int other = __shfl_down((int)cv.s, 1);
      if ((l16 & 1) == 0)
        astore64(hn + (size_t)m*(H_/2) + (j>>1),
                 ((u64)otag<<32) | (u64)(((u32)cv.s) | ((u32)other << 16)));
    }

    // --- deferred outcat stores (off the inter-block critical path) ---
#pragma unroll
    for (int r = 0; r < 4; ++r){
      int m = m0 + quad*4 + r;
      FU cv; cv.f = (f16)hprev[r];
      int other = __shfl_down((int)cv.s, 1);
      if ((l16 & 1) == 0)
        *(u32*)(outcat + ((size_t)t*B_ + m)*D1_ + dir*H_ + j) = (u32)cv.s | ((u32)other << 16);
    }
  }
}

// ---------------- phase C recurrence: layer-1 reverse over one CH-step chunk ----------------
// grid (2,32) = 64 blocks. Same tagged-u64 h exchange as phase A.

__global__ __launch_bounds__(256, 1) void k_phaseCrec(
    const f16* __restrict__ Z1c, const f16* __restrict__ w1h,
    const int* __restrict__ len,
    u64* __restrict__ hx1T, float* __restrict__ cstate, float* __restrict__ h1f,
    int s0, int CH)
{
  __shared__ f16 Wh[64*512];   // 64 KB
  const int half = blockIdx.x, jb = blockIdx.y;
  const int tid = threadIdx.x;
  const int w = tid>>6, lane = tid&63, quad = lane>>4, l16 = lane&15;
  const int j0 = jb*16;
  const int m0 = half*64 + w*16;

  for (int u = tid; u < 4096; u += 256){
    int lrr = u>>6, uc = u&63;
    int g = lrr>>4, i = lrr&15;
    *(uint4*)&Wh[lrr*512 + (uc ^ (i&7))*8] =
        *(const uint4*)(w1h + ((size_t)(g*H_ + j0 + i))*H_ + uc*8);
  }
  __syncthreads();

  const int j = j0 + l16;
  float hprev[4], cpr[4]; int lm[4];
#pragma unroll
  for (int r = 0; r < 4; ++r){
    int m = m0 + quad*4 + r;
    lm[r] = len[m];
    cpr[r] = cstate[(size_t)m*H_ + j];
    u64 qq = hx1T[(size_t)(s0 & 1)*NP_ + (size_t)m*(H_/2) + (j>>1)];
    FU fu; fu.s = (unsigned short)((j & 1) ? ((u32)qq >> 16) : ((u32)qq & 0xFFFFu));
    hprev[r] = (float)fu.f;
  }

  for (int sl = 0; sl < CH; ++sl){
    const int s = s0 + sl;
    const int t = S_-1-s;
    const int zrow = CH-1-sl;

    // --- prefetch Z rows (h-independent; overlaps publish latency) ---
    float zv[4][4];
#pragma unroll
    for (int g = 0; g < 4; ++g)
#pragma unroll
      for (int r = 0; r < 4; ++r)
        zv[g][r] = (float)Z1c[((size_t)zrow*B_ + m0 + quad*4 + r)*G_ + g*H_ + j];

    // --- h @ Whh1^T (K=512), tagged pipeline ---
    const int par = s & 1;
    const u32 exp = (u32)s;
    const u64* hrow = hx1T + (size_t)par*NP_ + (size_t)(m0 + l16)*(H_/2);
    f32x4 z4 = {0.f,0.f,0.f,0.f};
    f32x4 acc[4] = {z4,z4,z4,z4};
    u64 q[2][16];
#pragma unroll
    for (int kk = 0; kk < 4; ++kk)
#pragma unroll
      for (int e = 0; e < 4; ++e)
        q[0][kk*4+e] = aload64(hrow + kk*16 + quad*4 + e);
#pragma unroll
    for (int c = 0; c < 4; ++c){
      if (c < 3){
#pragma unroll
        for (int kk = 0; kk < 4; ++kk)
#pragma unroll
          for (int e = 0; e < 4; ++e)
            q[(c+1)&1][kk*4+e] = aload64(hrow + (c+1)*64 + kk*16 + quad*4 + e);
      }
      for (;;){
        bool ok = true;
#pragma unroll
        for (int i2 = 0; i2 < 16; ++i2) ok &= ((u32)(q[c&1][i2]>>32) == exp);
        if (ok) break;
#pragma unroll
        for (int kk = 0; kk < 4; ++kk)
#pragma unroll
          for (int e = 0; e < 4; ++e)
            q[c&1][kk*4+e] = aload64(hrow + c*64 + kk*16 + quad*4 + e);
      }
#pragma unroll
      for (int kk = 0; kk < 4; ++kk){
        H16 ha;
#pragma unroll
        for (int e = 0; e < 4; ++e) ha.w[e] = (u32)q[c&1][kk*4+e];
        int uq = (c*4+kk)*4 + quad;
#pragma unroll
        for (int g = 0; g < 4; ++g){
          f16x8 b = *(const f16x8*)&Wh[(g*16+l16)*512 + ((uq ^ (l16&7)))*8];
          acc[g] = __builtin_amdgcn_mfma_f32_16x16x32_f16(ha.v, b, acc[g],0,0,0);
        }
      }
    }

    u64* hn = hx1T + (size_t)(1-par)*NP_;
    const u32 otag = (u32)(s+1);
#pragma unroll
    for (int r = 0; r < 4; ++r){
      int m = m0 + quad*4 + r;
      float zi = acc[0][r] + zv[0][r];
      float zf = acc[1][r] + zv[1][r];
      float zg = acc[2][r] + zv[2][r];
      float zo = acc[3][r] + zv[3][r];
      float ig = sigf(zi), fg = sigf(zf), gg = tanhf_(zg), og = sigf(zo);
      float cnew = fg*cpr[r] + ig*gg;
      float hnew = og*tanhf_(cnew);
      bool mk = t < lm[r];
      float hsel = mk ? hnew : hprev[r];
      cpr[r] = mk ? cnew : cpr[r];
      hprev[r] = hsel;
      FU cv; cv.f = (f16)hsel;
      int other = __shfl_down((int)cv.s, 1);
      if ((l16 & 1) == 0)
        astore64(hn + (size_t)m*(H_/2) + (j>>1),
                 ((u64)otag<<32) | (u64)(((u32)cv.s) | ((u32)other << 16)));
    }

    if (t == 0){  // deferred final-state write (consumed by k_final after kernel end)
#pragma unroll
      for (int r = 0; r < 4; ++r)
        h1f[(size_t)(m0 + quad*4 + r)*H_ + j] = hprev[r];
    }
  }

  // persist c across chunk launches (h lives in hx1 parity buffers)
#pragma unroll
  for (int r = 0; r < 4; ++r)
    cstate[(size_t)(m0 + quad*4 + r)*H_ + j] = cpr[r];
}

// ---------------- epilogue: folded FC ----------------

__global__ void k_fold(const float* __restrict__ fc1w, const float* __restrict__ fc1b,
                       const float* __restrict__ fcw,  const float* __restrict__ fcb,
                       float* __restrict__ Mf, float* __restrict__ bf){
  int i = blockIdx.x*blockDim.x + threadIdx.x;
  if (i >= 1024) return;
  int o = i >> 9, h = i & 511;
  float s = 0.f;
  for (int jj = 0; jj < 512; ++jj) s += fcw[o*512 + jj] * fc1w[jj*512 + h];
  Mf[o*512 + h] = s;
  if (h == 0){
    float sb = fcb[o];
    for (int jj = 0; jj < 512; ++jj) sb += fcw[o*512 + jj] * fc1b[jj];
    bf[o] = sb;
  }
}

__global__ void k_final(const float* __restrict__ h1f, const float* __restrict__ Mf,
                        const float* __restrict__ bf, float* __restrict__ out){
  int i = threadIdx.x;
  if (i >= 256) return;
  int b = i >> 1, o = i & 1;
  float s = bf[o];
  const float* hp = h1f + (size_t)b*512;
  const float* mp = Mf + (size_t)o*512;
  for (int h = 0; h < 512; ++h) s += hp[h]*mp[h];
  out[b*2 + o] = s;
}

// ---------------- host ----------------

extern "C" void kernel_launch(void* const* d_in, const int* in_sizes, int n_in,
                              void* d_out, int out_size, void* d_ws, size_t ws_size,
                              hipStream_t stream)
{
  const float* x     = (const float*)d_in[0];
  const float* wih0f = (const float*)d_in[1];
  const float* whh0f = (const float*)d_in[2];
  const float* bih0f = (const float*)d_in[3];
  const float* bhh0f = (const float*)d_in[4];
  const float* wih0r = (const float*)d_in[5];
  const float* whh0r = (const float*)d_in[6];
  const float* bih0r = (const float*)d_in[7];
  const float* bhh0r = (const float*)d_in[8];
  // d_in[9..12] = layer1 forward: dead code (only hT_r of layer1 reaches output)
  const float* wih1r = (const float*)d_in[13];
  const float* whh1r = (const float*)d_in[14];
  const float* bih1r = (const float*)d_in[15];
  const float* bhh1r = (const float*)d_in[16];
  const float* fc1w  = (const float*)d_in[17];
  const float* fc1b  = (const float*)d_in[18];
  const float* fcw   = (const float*)d_in[19];
  const float* fcb   = (const float*)d_in[20];
  float* out = (float*)d_out;

  char* p = (char*)d_ws;
  auto alloc = [&](size_t bytes)->char*{
    char* r = p; p += (bytes + 255) & ~(size_t)255; return r;
  };
  f16* w0fp   = (f16*)alloc((size_t)G_*EP_*2);       // 1.3 MB
  f16* w0rp   = (f16*)alloc((size_t)G_*EP_*2);
  f16* whf    = (f16*)alloc((size_t)G_*H_*2);        // 2 MB
  f16* whr    = (f16*)alloc((size_t)G_*H_*2);
  f16* w1i    = (f16*)alloc((size_t)G_*D1_*2);       // 4 MB
  f16* w1h    = (f16*)alloc((size_t)G_*H_*2);        // 2 MB
  float* bs0  = (float*)alloc((size_t)2*G_*4);
  float* bs1r = (float*)alloc(G_*4);
  int*   len  = (int*)alloc(B_*4);
  f16* outcat = (f16*)alloc((size_t)S_*B_*D1_*2);    // 67 MB
  u64* hxT    = (u64*)alloc((size_t)2*2*NP_*8);      // 1 MB tagged [dir][par]
  u64* hx1T   = (u64*)alloc((size_t)2*NP_*8);        // 512 KB tagged [par]
  float* cstate=(float*)alloc((size_t)B_*H_*4);
  float* h1f  = (float*)alloc((size_t)B_*H_*4);
  float* Mf   = (float*)alloc(2*512*4);
  float* bf   = (float*)alloc(256);
  // fixed ~82 MB; Z1c chunk adaptive (ws >= ~90 MB proven by round 2)
  size_t used = (size_t)(p - (char*)d_ws);
  int CH = 8;
  for (int c = 256; c >= 8; c >>= 1){
    if (used + (size_t)c*B_*G_*2 <= ws_size){ CH = c; break; }
  }
  f16* Z1c = (f16*)alloc((size_t)CH*B_*G_*2);
  const int NC = S_/CH;

  int n;
  n = G_*EP_; k_pad_w<<<(n+255)/256, 256, 0, stream>>>(wih0f, w0fp, G_, E_, EP_);
              k_pad_w<<<(n+255)/256, 256, 0, stream>>>(wih0r, w0rp, G_, E_, EP_);
  n = G_*H_;  k_f32_to_f16<<<(n+255)/256,256,0,stream>>>(whh0f, whf, n);
              k_f32_to_f16<<<(n+255)/256,256,0,stream>>>(whh0r, whr, n);
              k_f32_to_f16<<<(n+255)/256,256,0,stream>>>(whh1r, w1h, n);
  n = G_*D1_; k_f32_to_f16<<<(n+255)/256,256,0,stream>>>(wih1r, w1i, n);
  k_bias<<<8,256,0,stream>>>(bih0f, bhh0f, bs0, G_);
  k_bias<<<8,256,0,stream>>>(bih0r, bhh0r, bs0 + G_, G_);
  k_bias<<<8,256,0,stream>>>(bih1r, bhh1r, bs1r, G_);
  k_len<<<1,128,0,stream>>>(x, len);
  k_init<<<(B_*H_+255)/256,256,0,stream>>>(hxT, hx1T, cstate);
  k_fold<<<4,256,0,stream>>>(fc1w, fc1b, fcw, fcb, Mf, bf);

  // ---- phase A: layer-0 fwd+rev, single persistent launch ----
  k_phaseA<<<dim3(2,32,2), 256, 0, stream>>>(
      x, w0fp, w0rp, whf, whr, bs0, len, hxT, outcat);

  // ---- phase C: per chunk, dense Z1 GEMM then recurrence ----
  for (int cc = 0; cc < NC; ++cc){
    int t0 = S_ - (cc+1)*CH;     // chunk covers t in [t0, t0+CH), consumed descending
    k_gemm_bt<<<dim3(CH*2,32), 256, 0, stream>>>(
        outcat + (size_t)t0*B_*D1_, w1i, Z1c, bs1r, CH*B_, G_, D1_);
    k_phaseCrec<<<dim3(2,32), 256, 0, stream>>>(
        Z1c, w1h, len, hx1T, cstate, h1f, cc*CH, CH);
  }

  k_final<<<1,256,0,stream>>>(h1f, Mf, bf, out);
}

// Round 5
// 4667.071 us; speedup vs baseline: 1.4572x; 1.4572x over previous
//
#include <hip/hip_runtime.h>

#define B_  128
#define S_  256
#define E_  300
#define EP_ 320
#define H_  512
#define G_  2048   // 4*H
#define D1_ 1024   // 2*H

typedef _Float16 f16;
typedef __attribute__((ext_vector_type(8))) _Float16 f16x8;
typedef __attribute__((ext_vector_type(4))) float    f32x4;
typedef unsigned long long u64;
typedef unsigned int u32;

__device__ __forceinline__ float sigf(float x){ return 1.f/(1.f + __expf(-x)); }
__device__ __forceinline__ float tanhf_(float x){
  float e = __expf(-2.f*fabsf(x));
  float t = (1.f - e)/(1.f + e);
  return x < 0.f ? -t : t;
}

// Relaxed agent-scope atomics: route to the coherence point (IF$), bypassing the
// non-coherent per-XCD L2s; no acquire/release -> no buffer_wbl2/inv -> L2 stays
// warm for the weight streams.
// Round-4 lesson: handshake variants (flags R2, tagged-data R4) are all WORSE
// than R1's fetch_add+poll -> sync was never the bottleneck. The 11us/step is
// the h-GEMM's 16 serialized IF$ round-trips ({2 loads -> 4 dep MFMA} x16).
// This round: batch all 32 atomic loads into registers BEFORE the MFMAs so the
// IF$ latency is paid once, pipelined, instead of 16 times.
__device__ __forceinline__ u64 aload64(const u64* p){
  return __hip_atomic_load((u64*)p, __ATOMIC_RELAXED, __HIP_MEMORY_SCOPE_AGENT);
}
__device__ __forceinline__ void astore32(u32* p, u32 v){
  __hip_atomic_store(p, v, __ATOMIC_RELAXED, __HIP_MEMORY_SCOPE_AGENT);
}
union H8 { u64 q[2]; f16x8 v; };
union FU { f16 f; unsigned short s; };

// ---------------- setup kernels ----------------

__global__ void k_f32_to_f16(const float* __restrict__ s, f16* __restrict__ d, int n){
  int i = blockIdx.x*blockDim.x + threadIdx.x;
  if (i < n) d[i] = (f16)s[i];
}

__global__ void k_pad_w(const float* __restrict__ s, f16* __restrict__ d, int rows, int ks, int kd){
  int i = blockIdx.x*blockDim.x + threadIdx.x;
  if (i >= rows*kd) return;
  int r = i/kd, k = i - r*kd;
  d[i] = (k < ks) ? (f16)s[(size_t)r*ks + k] : (f16)0.f;
}

__global__ void k_bias(const float* __restrict__ a, const float* __restrict__ b,
                       float* __restrict__ d, int n){
  int i = blockIdx.x*blockDim.x + threadIdx.x;
  if (i < n) d[i] = a[i] + b[i];
}

__global__ void k_len(const float* __restrict__ x, int* __restrict__ len){
  int b = threadIdx.x;
  if (b < B_){
    int v = (int)x[((size_t)b*S_ + (S_-1))*E_];
    len[b] = v > S_ ? S_ : v;
  }
}

// hxA: [dir][parity][B*H], hx1: [parity][B*H]; parity-0 = h0 = 1. cstate = c0 = 1.
__global__ void k_init(f16* hxA, f16* hx1, float* cstate, u32* barA, u32* barC){
  int i = blockIdx.x*blockDim.x + threadIdx.x;
  if (i < B_*H_){
    hxA[i] = (f16)1.f;                // dir0 par0
    hxA[2*B_*H_ + i] = (f16)1.f;      // dir1 par0
    hx1[i] = (f16)1.f;                // par0
    cstate[i] = 1.f;
  }
  if (i < 4*S_) barA[i] = 0u;
  if (i < 2*S_) barC[i] = 0u;
}

// ---------------- GEMM: C[M,N] = A[M,K] @ B[N,K]^T + bias (f16 in/out, fp32 acc) ----------------

__global__ __launch_bounds__(256) void k_gemm_bt(
    const f16* __restrict__ A, const f16* __restrict__ Bm,
    f16* __restrict__ C, const float* __restrict__ bias,
    int M, int N, int K)
{
  __shared__ f16 As[64*40];
  __shared__ f16 Bs[64*40];
  const int m0 = blockIdx.x*64, n0 = blockIdx.y*64;
  const int tid = threadIdx.x;
  const int w = tid>>6, lane = tid&63, quad = lane>>4, l16 = lane&15;
  const int wm = (w&1)*32, wn = (w>>1)*32;
  const int lr = tid>>2, lc = (tid&3)*8;
  const f16* Ap = A + (size_t)(m0+lr)*K + lc;
  const f16* Bp = Bm + (size_t)(n0+lr)*K + lc;
  f32x4 z4 = {0.f,0.f,0.f,0.f};
  f32x4 acc[2][2] = {{z4,z4},{z4,z4}};
  for (int k0 = 0; k0 < K; k0 += 32){
    *(uint4*)&As[lr*40+lc] = *(const uint4*)(Ap + k0);
    *(uint4*)&Bs[lr*40+lc] = *(const uint4*)(Bp + k0);
    __syncthreads();
    f16x8 a0 = *(const f16x8*)&As[(wm+l16)*40 + quad*8];
    f16x8 a1 = *(const f16x8*)&As[(wm+16+l16)*40 + quad*8];
    f16x8 b0 = *(const f16x8*)&Bs[(wn+l16)*40 + quad*8];
    f16x8 b1 = *(const f16x8*)&Bs[(wn+16+l16)*40 + quad*8];
    acc[0][0] = __builtin_amdgcn_mfma_f32_16x16x32_f16(a0,b0,acc[0][0],0,0,0);
    acc[0][1] = __builtin_amdgcn_mfma_f32_16x16x32_f16(a0,b1,acc[0][1],0,0,0);
    acc[1][0] = __builtin_amdgcn_mfma_f32_16x16x32_f16(a1,b0,acc[1][0],0,0,0);
    acc[1][1] = __builtin_amdgcn_mfma_f32_16x16x32_f16(a1,b1,acc[1][1],0,0,0);
    __syncthreads();
  }
#pragma unroll
  for (int mi = 0; mi < 2; ++mi)
#pragma unroll
    for (int ni = 0; ni < 2; ++ni){
      int col = n0 + wn + ni*16 + l16;
      float bz = bias[col];
#pragma unroll
      for (int r = 0; r < 4; ++r){
        int row = m0 + wm + mi*16 + quad*4 + r;
        C[(size_t)row*N + col] = (f16)(acc[mi][ni][r] + bz);
      }
    }
}

// ---------------- phase A: persistent layer-0 fwd+rev, column-partitioned ----------------
// grid (2,32,2) = 128 blocks, 256 thr. Block: 64 batch rows x 16 hidden x 4 gates.
// W_hh slice in LDS (64KB staged once); W_ih slice streamed from L2; h exchanged
// via IF$ relaxed atomics; per-step slot flag per (dir,half) group of 32 blocks.
// Round-5 change vs R1: h-GEMM loads are batch-issued into registers (hq[32])
// before any consuming MFMA -> one pipelined IF$ latency instead of 16 serial.

__global__ __launch_bounds__(256, 1) void k_phaseA(
    const float* __restrict__ x,
    const f16* __restrict__ w0f, const f16* __restrict__ w0r,
    const f16* __restrict__ whf, const f16* __restrict__ whr,
    const float* __restrict__ bs0, const int* __restrict__ len,
    f16* __restrict__ hxA, f16* __restrict__ outcat,
    u32* __restrict__ barA)
{
  __shared__ f16 Wh[64*512];   // exactly 64 KB
  const int half = blockIdx.x, jb = blockIdx.y, dir = blockIdx.z;
  const f16* wih = dir ? w0r : w0f;
  const f16* whh = dir ? whr : whf;
  const float* bias = bs0 + dir*G_;
  f16* hx = hxA + (size_t)dir*(2*B_*H_);
  u32* mybar = barA + (dir*2 + half)*S_;
  const int tid = threadIdx.x;
  const int w = tid>>6, lane = tid&63, quad = lane>>4, l16 = lane&15;
  const int j0 = jb*16;
  const int m0 = half*64 + w*16;       // this wave's 16 batch rows

  for (int u = tid; u < 4096; u += 256){
    int lrr = u>>6, uc = u&63;
    int g = lrr>>4, i = lrr&15;
    *(uint4*)&Wh[lrr*512 + (uc ^ (i&7))*8] =
        *(const uint4*)(whh + ((size_t)(g*H_ + j0 + i))*H_ + uc*8);
  }
  __syncthreads();

  const int j = j0 + l16;
  const f16* wiB[4];
#pragma unroll
  for (int g = 0; g < 4; ++g) wiB[g] = wih + (size_t)(g*H_ + j)*EP_ + quad*8;
  float bz[4], hprev[4], cpr[4]; int lm[4];
#pragma unroll
  for (int g = 0; g < 4; ++g) bz[g] = bias[g*H_ + j];
#pragma unroll
  for (int r = 0; r < 4; ++r){ hprev[r] = 1.f; cpr[r] = 1.f; lm[r] = len[m0 + quad*4 + r]; }
  const size_t xrowbase = (size_t)(m0 + l16)*S_;

  for (int s = 0; s < S_; ++s){
    const int t = dir ? (S_-1-s) : s;
    f32x4 z4 = {0.f,0.f,0.f,0.f};
    f32x4 acc[4] = {z4,z4,z4,z4};

    // --- x_t @ Wih^T (h-independent; overlaps the barrier wait) ---
    const float* xr = x + (xrowbase + t)*E_;
#pragma unroll
    for (int kb = 0; kb < 9; ++kb){
      float4 f0 = *(const float4*)(xr + kb*32 + quad*8);
      float4 f1 = *(const float4*)(xr + kb*32 + quad*8 + 4);
      f16x8 a;
      a[0]=(f16)f0.x; a[1]=(f16)f0.y; a[2]=(f16)f0.z; a[3]=(f16)f0.w;
      a[4]=(f16)f1.x; a[5]=(f16)f1.y; a[6]=(f16)f1.z; a[7]=(f16)f1.w;
#pragma unroll
      for (int g = 0; g < 4; ++g)
        acc[g] = __builtin_amdgcn_mfma_f32_16x16x32_f16(a, *(const f16x8*)(wiB[g] + kb*32), acc[g],0,0,0);
    }
    { // K tail 288..319 (x valid to 299; weight pad cols are zero)
      int kbase = 288 + quad*8;
      f16x8 a;
#pragma unroll
      for (int e2 = 0; e2 < 8; ++e2)
        a[e2] = (kbase + e2 < E_) ? (f16)xr[kbase + e2] : (f16)0.f;
#pragma unroll
      for (int g = 0; g < 4; ++g)
        acc[g] = __builtin_amdgcn_mfma_f32_16x16x32_f16(a, *(const f16x8*)(wiB[g] + 288), acc[g],0,0,0);
    }

    // --- uniform per-wave poll (one broadcast load; waves proceed independently) ---
    if (s > 0){
      while (__hip_atomic_load(&mybar[s-1], __ATOMIC_RELAXED, __HIP_MEMORY_SCOPE_AGENT) < 32u) {}
    }
    asm volatile("" ::: "memory");   // keep h loads below the poll

    // --- h @ Whh^T (K=512): batch-issue ALL 32 IF$ loads, then MFMA ---
    const int par = s & 1;
    const u64* hap = (const u64*)(hx + (size_t)par*(B_*H_) + (size_t)(m0 + l16)*H_);
    u64 hq[32];
#pragma unroll
    for (int kb = 0; kb < 16; ++kb){
      hq[2*kb]   = aload64(hap + kb*8 + quad*2);
      hq[2*kb+1] = aload64(hap + kb*8 + quad*2 + 1);
    }
#pragma unroll
    for (int kb = 0; kb < 16; ++kb){
      H8 ha;
      ha.q[0] = hq[2*kb];
      ha.q[1] = hq[2*kb+1];
      int uq = kb*4 + quad;
#pragma unroll
      for (int g = 0; g < 4; ++g){
        f16x8 b = *(const f16x8*)&Wh[(g*16+l16)*512 + ((uq ^ (l16&7)))*8];
        acc[g] = __builtin_amdgcn_mfma_f32_16x16x32_f16(ha.v, b, acc[g],0,0,0);
      }
    }

    // --- gates + state update; publish h via IF$ (packed 4B, even lanes) ---
    f16* hn = hx + (size_t)(1-par)*(B_*H_);
#pragma unroll
    for (int r = 0; r < 4; ++r){
      int m = m0 + quad*4 + r;
      float zi = acc[0][r] + bz[0];
      float zf = acc[1][r] + bz[1];
      float zg = acc[2][r] + bz[2];
      float zo = acc[3][r] + bz[3];
      float ig = sigf(zi), fg = sigf(zf), gg = tanhf_(zg), og = sigf(zo);
      float cnew = fg*cpr[r] + ig*gg;
      float hnew = og*tanhf_(cnew);
      bool mk = t < lm[r];
      float hsel = mk ? hnew : hprev[r];
      cpr[r] = mk ? cnew : cpr[r];
      hprev[r] = hsel;
      FU cv; cv.f = (f16)hsel;
      int other = __shfl_down((int)cv.s, 1);
      if ((l16 & 1) == 0)
        astore32((u32*)(hn + (size_t)m*H_ + j), (u32)cv.s | ((u32)other << 16));
    }
    __syncthreads();   // drains h atomic stores (vmcnt(0) before s_barrier)
    if (tid == 0)
      __hip_atomic_fetch_add(&mybar[s], 1u, __ATOMIC_RELAXED, __HIP_MEMORY_SCOPE_AGENT);

    // --- deferred outcat stores (off the inter-block critical path) ---
#pragma unroll
    for (int r = 0; r < 4; ++r){
      int m = m0 + quad*4 + r;
      FU cv; cv.f = (f16)hprev[r];
      int other = __shfl_down((int)cv.s, 1);
      if ((l16 & 1) == 0)
        *(u32*)(outcat + ((size_t)t*B_ + m)*D1_ + dir*H_ + j) = (u32)cv.s | ((u32)other << 16);
    }
  }
}

// ---------------- phase C recurrence: layer-1 reverse over one CH-step chunk ----------------
// grid (2,32) = 64 blocks. Z1c (x-part + bias) precomputed by dense GEMM -> this
// kernel is only the K=512 h-GEMM + gates. Same batch-load change as phase A.

__global__ __launch_bounds__(256, 1) void k_phaseCrec(
    const f16* __restrict__ Z1c, const f16* __restrict__ w1h,
    const int* __restrict__ len,
    f16* __restrict__ hx1, float* __restrict__ cstate, float* __restrict__ h1f,
    u32* __restrict__ barC, int s0, int CH)
{
  __shared__ f16 Wh[64*512];   // 64 KB
  const int half = blockIdx.x, jb = blockIdx.y;
  u32* mybar = barC + half*S_;
  const int tid = threadIdx.x;
  const int w = tid>>6, lane = tid&63, quad = lane>>4, l16 = lane&15;
  const int j0 = jb*16;
  const int m0 = half*64 + w*16;

  for (int u = tid; u < 4096; u += 256){
    int lrr = u>>6, uc = u&63;
    int g = lrr>>4, i = lrr&15;
    *(uint4*)&Wh[lrr*512 + (uc ^ (i&7))*8] =
        *(const uint4*)(w1h + ((size_t)(g*H_ + j0 + i))*H_ + uc*8);
  }
  __syncthreads();

  const int j = j0 + l16;
  float hprev[4], cpr[4]; int lm[4];
#pragma unroll
  for (int r = 0; r < 4; ++r){
    int m = m0 + quad*4 + r;
    lm[r] = len[m];
    cpr[r] = cstate[(size_t)m*H_ + j];
    hprev[r] = (float)hx1[(size_t)(s0 & 1)*(B_*H_) + (size_t)m*H_ + j];
  }

  for (int sl = 0; sl < CH; ++sl){
    const int s = s0 + sl;
    const int t = S_-1-s;
    const int zrow = CH-1-sl;

    // --- prefetch Z rows (h-independent; overlaps the wait) ---
    float zv[4][4];
#pragma unroll
    for (int g = 0; g < 4; ++g)
#pragma unroll
      for (int r = 0; r < 4; ++r)
        zv[g][r] = (float)Z1c[((size_t)zrow*B_ + m0 + quad*4 + r)*G_ + g*H_ + j];

    if (s > 0){
      while (__hip_atomic_load(&mybar[s-1], __ATOMIC_RELAXED, __HIP_MEMORY_SCOPE_AGENT) < 32u) {}
    }
    asm volatile("" ::: "memory");

    // --- h @ Whh1^T (K=512): batch-issue loads, then MFMA ---
    const int par = s & 1;
    const u64* hap = (const u64*)(hx1 + (size_t)par*(B_*H_) + (size_t)(m0 + l16)*H_);
    f32x4 z4 = {0.f,0.f,0.f,0.f};
    f32x4 acc[4] = {z4,z4,z4,z4};
    u64 hq[32];
#pragma unroll
    for (int kb = 0; kb < 16; ++kb){
      hq[2*kb]   = aload64(hap + kb*8 + quad*2);
      hq[2*kb+1] = aload64(hap + kb*8 + quad*2 + 1);
    }
#pragma unroll
    for (int kb = 0; kb < 16; ++kb){
      H8 ha;
      ha.q[0] = hq[2*kb];
      ha.q[1] = hq[2*kb+1];
      int uq = kb*4 + quad;
#pragma unroll
      for (int g = 0; g < 4; ++g){
        f16x8 b = *(const f16x8*)&Wh[(g*16+l16)*512 + ((uq ^ (l16&7)))*8];
        acc[g] = __builtin_amdgcn_mfma_f32_16x16x32_f16(ha.v, b, acc[g],0,0,0);
      }
    }

    f16* hn = hx1 + (size_t)(1-par)*(B_*H_);
#pragma unroll
    for (int r = 0; r < 4; ++r){
      int m = m0 + quad*4 + r;
      float zi = acc[0][r] + zv[0][r];
      float zf = acc[1][r] + zv[1][r];
      float zg = acc[2][r] + zv[2][r];
      float zo = acc[3][r] + zv[3][r];
      float ig = sigf(zi), fg = sigf(zf), gg = tanhf_(zg), og = sigf(zo);
      float cnew = fg*cpr[r] + ig*gg;
      float hnew = og*tanhf_(cnew);
      bool mk = t < lm[r];
      float hsel = mk ? hnew : hprev[r];
      cpr[r] = mk ? cnew : cpr[r];
      hprev[r] = hsel;
      FU cv; cv.f = (f16)hsel;
      int other = __shfl_down((int)cv.s, 1);
      if ((l16 & 1) == 0)
        astore32((u32*)(hn + (size_t)m*H_ + j), (u32)cv.s | ((u32)other << 16));
    }
    __syncthreads();
    if (tid == 0)
      __hip_atomic_fetch_add(&mybar[s], 1u, __ATOMIC_RELAXED, __HIP_MEMORY_SCOPE_AGENT);

    if (t == 0){  // deferred final-state write (consumed by k_final after kernel end)
#pragma unroll
      for (int r = 0; r < 4; ++r)
        h1f[(size_t)(m0 + quad*4 + r)*H_ + j] = hprev[r];
    }
  }

  // persist c across chunk launches (h lives in hx1 parity buffers)
#pragma unroll
  for (int r = 0; r < 4; ++r)
    cstate[(size_t)(m0 + quad*4 + r)*H_ + j] = cpr[r];
}

// ---------------- epilogue: folded FC ----------------

__global__ void k_fold(const float* __restrict__ fc1w, const float* __restrict__ fc1b,
                       const float* __restrict__ fcw,  const float* __restrict__ fcb,
                       float* __restrict__ Mf, float* __restrict__ bf){
  int i = blockIdx.x*blockDim.x + threadIdx.x;
  if (i >= 1024) return;
  int o = i >> 9, h = i & 511;
  float s = 0.f;
  for (int jj = 0; jj < 512; ++jj) s += fcw[o*512 + jj] * fc1w[jj*512 + h];
  Mf[o*512 + h] = s;
  if (h == 0){
    float sb = fcb[o];
    for (int jj = 0; jj < 512; ++jj) sb += fcw[o*512 + jj] * fc1b[jj];
    bf[o] = sb;
  }
}

__global__ void k_final(const float* __restrict__ h1f, const float* __restrict__ Mf,
                        const float* __restrict__ bf, float* __restrict__ out){
  int i = threadIdx.x;
  if (i >= 256) return;
  int b = i >> 1, o = i & 1;
  float s = bf[o];
  const float* hp = h1f + (size_t)b*512;
  const float* mp = Mf + (size_t)o*512;
  for (int h = 0; h < 512; ++h) s += hp[h]*mp[h];
  out[b*2 + o] = s;
}

// ---------------- host ----------------

extern "C" void kernel_launch(void* const* d_in, const int* in_sizes, int n_in,
                              void* d_out, int out_size, void* d_ws, size_t ws_size,
                              hipStream_t stream)
{
  const float* x     = (const float*)d_in[0];
  const float* wih0f = (const float*)d_in[1];
  const float* whh0f = (const float*)d_in[2];
  const float* bih0f = (const float*)d_in[3];
  const float* bhh0f = (const float*)d_in[4];
  const float* wih0r = (const float*)d_in[5];
  const float* whh0r = (const float*)d_in[6];
  const float* bih0r = (const float*)d_in[7];
  const float* bhh0r = (const float*)d_in[8];
  // d_in[9..12] = layer1 forward: dead code (only hT_r of layer1 reaches output)
  const float* wih1r = (const float*)d_in[13];
  const float* whh1r = (const float*)d_in[14];
  const float* bih1r = (const float*)d_in[15];
  const float* bhh1r = (const float*)d_in[16];
  const float* fc1w  = (const float*)d_in[17];
  const float* fc1b  = (const float*)d_in[18];
  const float* fcw   = (const float*)d_in[19];
  const float* fcb   = (const float*)d_in[20];
  float* out = (float*)d_out;

  char* p = (char*)d_ws;
  auto alloc = [&](size_t bytes)->char*{
    char* r = p; p += (bytes + 255) & ~(size_t)255; return r;
  };
  f16* w0fp   = (f16*)alloc((size_t)G_*EP_*2);       // 1.3 MB
  f16* w0rp   = (f16*)alloc((size_t)G_*EP_*2);
  f16* whf    = (f16*)alloc((size_t)G_*H_*2);        // 2 MB
  f16* whr    = (f16*)alloc((size_t)G_*H_*2);
  f16* w1i    = (f16*)alloc((size_t)G_*D1_*2);       // 4 MB
  f16* w1h    = (f16*)alloc((size_t)G_*H_*2);        // 2 MB
  float* bs0  = (float*)alloc((size_t)2*G_*4);
  float* bs1r = (float*)alloc(G_*4);
  int*   len  = (int*)alloc(B_*4);
  f16* outcat = (f16*)alloc((size_t)S_*B_*D1_*2);    // 67 MB
  f16* hxA    = (f16*)alloc((size_t)2*2*B_*H_*2);
  f16* hx1    = (f16*)alloc((size_t)2*B_*H_*2);
  float* cstate=(float*)alloc((size_t)B_*H_*4);
  float* h1f  = (float*)alloc((size_t)B_*H_*4);
  float* Mf   = (float*)alloc(2*512*4);
  float* bf   = (float*)alloc(256);
  u32* barA   = (u32*)alloc(4*S_*4);
  u32* barC   = (u32*)alloc(2*S_*4);
  // fixed ~81 MB; Z1c chunk adaptive
  size_t used = (size_t)(p - (char*)d_ws);
  int CH = 8;
  for (int c = 256; c >= 8; c >>= 1){
    if (used + (size_t)c*B_*G_*2 <= ws_size){ CH = c; break; }
  }
  f16* Z1c = (f16*)alloc((size_t)CH*B_*G_*2);
  const int NC = S_/CH;

  int n;
  n = G_*EP_; k_pad_w<<<(n+255)/256, 256, 0, stream>>>(wih0f, w0fp, G_, E_, EP_);
              k_pad_w<<<(n+255)/256, 256, 0, stream>>>(wih0r, w0rp, G_, E_, EP_);
  n = G_*H_;  k_f32_to_f16<<<(n+255)/256,256,0,stream>>>(whh0f, whf, n);
              k_f32_to_f16<<<(n+255)/256,256,0,stream>>>(whh0r, whr, n);
              k_f32_to_f16<<<(n+255)/256,256,0,stream>>>(whh1r, w1h, n);
  n = G_*D1_; k_f32_to_f16<<<(n+255)/256,256,0,stream>>>(wih1r, w1i, n);
  k_bias<<<8,256,0,stream>>>(bih0f, bhh0f, bs0, G_);
  k_bias<<<8,256,0,stream>>>(bih0r, bhh0r, bs0 + G_, G_);
  k_bias<<<8,256,0,stream>>>(bih1r, bhh1r, bs1r, G_);
  k_len<<<1,128,0,stream>>>(x, len);
  k_init<<<(B_*H_+255)/256,256,0,stream>>>(hxA, hx1, cstate, barA, barC);
  k_fold<<<4,256,0,stream>>>(fc1w, fc1b, fcw, fcb, Mf, bf);

  // ---- phase A: layer-0 fwd+rev, single persistent launch ----
  k_phaseA<<<dim3(2,32,2), 256, 0, stream>>>(
      x, w0fp, w0rp, whf, whr, bs0, len, hxA, outcat, barA);

  // ---- phase C: per chunk, dense Z1 GEMM then recurrence ----
  for (int cc = 0; cc < NC; ++cc){
    int t0 = S_ - (cc+1)*CH;     // chunk covers t in [t0, t0+CH), consumed descending
    k_gemm_bt<<<dim3(CH*2,32), 256, 0, stream>>>(
        outcat + (size_t)t0*B_*D1_, w1i, Z1c, bs1r, CH*B_, G_, D1_);
    k_phaseCrec<<<dim3(2,32), 256, 0, stream>>>(
        Z1c, w1h, len, hx1, cstate, h1f, barC, cc*CH, CH);
  }

  k_final<<<1,256,0,stream>>>(h1f, Mf, bf, out);
}

// Round 7
// 4276.957 us; speedup vs baseline: 1.5901x; 1.0912x over previous
//
#include <hip/hip_runtime.h>

#define B_  128
#define S_  256
#define E_  300
#define EP_ 320
#define H_  512
#define G_  2048   // 4*H
#define D1_ 1024   // 2*H

typedef _Float16 f16;
typedef __attribute__((ext_vector_type(8))) _Float16 f16x8;
typedef __attribute__((ext_vector_type(4))) float    f32x4;
typedef unsigned long long u64;
typedef unsigned int u32;

__device__ __forceinline__ float sigf(float x){ return 1.f/(1.f + __expf(-x)); }
__device__ __forceinline__ float tanhf_(float x){
  float e = __expf(-2.f*fabsf(x));
  float t = (1.f - e)/(1.f + e);
  return x < 0.f ? -t : t;
}

// Relaxed agent-scope atomics route to the coherence point, bypassing the
// non-coherent per-XCD L2s.
// R1-R5 ledger: sync variants (fetch_add R1 / write-once flags R2 / tagged R4)
// differ by only +-1.5us/step -> sync is NOT the bottleneck. Batch h-loads
// (R5) = -0.65us/step. MfmaUtil+VALUBusy say ~0.9us/step is execution; the
// other ~8us/step is un-overlapped memory latency in the step-top x-GEMM
// (serialized x(L3)+W(L2) loads feeding dependent MFMAs).
// R6: W_ih slice staged to LDS (once); x_t prefetched cross-step into raw f32
// regs (cvt deferred to consumption so the vmcnt wait lands next step).
__device__ __forceinline__ u64 aload64(const u64* p){
  return __hip_atomic_load((u64*)p, __ATOMIC_RELAXED, __HIP_MEMORY_SCOPE_AGENT);
}
__device__ __forceinline__ void astore32(u32* p, u32 v){
  __hip_atomic_store(p, v, __ATOMIC_RELAXED, __HIP_MEMORY_SCOPE_AGENT);
}
union H8 { u64 q[2]; f16x8 v; };
union FU { f16 f; unsigned short s; };

// ---------------- setup kernels ----------------

__global__ void k_f32_to_f16(const float* __restrict__ s, f16* __restrict__ d, int n){
  int i = blockIdx.x*blockDim.x + threadIdx.x;
  if (i < n) d[i] = (f16)s[i];
}

__global__ void k_pad_w(const float* __restrict__ s, f16* __restrict__ d, int rows, int ks, int kd){
  int i = blockIdx.x*blockDim.x + threadIdx.x;
  if (i >= rows*kd) return;
  int r = i/kd, k = i - r*kd;
  d[i] = (k < ks) ? (f16)s[(size_t)r*ks + k] : (f16)0.f;
}

__global__ void k_bias(const float* __restrict__ a, const float* __restrict__ b,
                       float* __restrict__ d, int n){
  int i = blockIdx.x*blockDim.x + threadIdx.x;
  if (i < n) d[i] = a[i] + b[i];
}

__global__ void k_len(const float* __restrict__ x, int* __restrict__ len){
  int b = threadIdx.x;
  if (b < B_){
    int v = (int)x[((size_t)b*S_ + (S_-1))*E_];
    len[b] = v > S_ ? S_ : v;
  }
}

// hxA: [dir][parity][B*H], hx1: [parity][B*H]; parity-0 = h0 = 1. cstate = c0 = 1.
__global__ void k_init(f16* hxA, f16* hx1, float* cstate, u32* barA, u32* barC){
  int i = blockIdx.x*blockDim.x + threadIdx.x;
  if (i < B_*H_){
    hxA[i] = (f16)1.f;                // dir0 par0
    hxA[2*B_*H_ + i] = (f16)1.f;      // dir1 par0
    hx1[i] = (f16)1.f;                // par0
    cstate[i] = 1.f;
  }
  if (i < 4*S_) barA[i] = 0u;
  if (i < 2*S_) barC[i] = 0u;
}

// ---------------- GEMM: C[M,N] = A[M,K] @ B[N,K]^T + bias (f16 in/out, fp32 acc) ----------------

__global__ __launch_bounds__(256) void k_gemm_bt(
    const f16* __restrict__ A, const f16* __restrict__ Bm,
    f16* __restrict__ C, const float* __restrict__ bias,
    int M, int N, int K)
{
  __shared__ f16 As[64*40];
  __shared__ f16 Bs[64*40];
  const int m0 = blockIdx.x*64, n0 = blockIdx.y*64;
  const int tid = threadIdx.x;
  const int w = tid>>6, lane = tid&63, quad = lane>>4, l16 = lane&15;
  const int wm = (w&1)*32, wn = (w>>1)*32;
  const int lr = tid>>2, lc = (tid&3)*8;
  const f16* Ap = A + (size_t)(m0+lr)*K + lc;
  const f16* Bp = Bm + (size_t)(n0+lr)*K + lc;
  f32x4 z4 = {0.f,0.f,0.f,0.f};
  f32x4 acc[2][2] = {{z4,z4},{z4,z4}};
  for (int k0 = 0; k0 < K; k0 += 32){
    *(uint4*)&As[lr*40+lc] = *(const uint4*)(Ap + k0);
    *(uint4*)&Bs[lr*40+lc] = *(const uint4*)(Bp + k0);
    __syncthreads();
    f16x8 a0 = *(const f16x8*)&As[(wm+l16)*40 + quad*8];
    f16x8 a1 = *(const f16x8*)&As[(wm+16+l16)*40 + quad*8];
    f16x8 b0 = *(const f16x8*)&Bs[(wn+l16)*40 + quad*8];
    f16x8 b1 = *(const f16x8*)&Bs[(wn+16+l16)*40 + quad*8];
    acc[0][0] = __builtin_amdgcn_mfma_f32_16x16x32_f16(a0,b0,acc[0][0],0,0,0);
    acc[0][1] = __builtin_amdgcn_mfma_f32_16x16x32_f16(a0,b1,acc[0][1],0,0,0);
    acc[1][0] = __builtin_amdgcn_mfma_f32_16x16x32_f16(a1,b0,acc[1][0],0,0,0);
    acc[1][1] = __builtin_amdgcn_mfma_f32_16x16x32_f16(a1,b1,acc[1][1],0,0,0);
    __syncthreads();
  }
#pragma unroll
  for (int mi = 0; mi < 2; ++mi)
#pragma unroll
    for (int ni = 0; ni < 2; ++ni){
      int col = n0 + wn + ni*16 + l16;
      float bz = bias[col];
#pragma unroll
      for (int r = 0; r < 4; ++r){
        int row = m0 + wm + mi*16 + quad*4 + r;
        C[(size_t)row*N + col] = (f16)(acc[mi][ni][r] + bz);
      }
    }
}

// ---------------- phase A: persistent layer-0 fwd+rev, column-partitioned ----------------
// grid (2,32,2) = 128 blocks, 256 thr. Block: 64 batch rows x 16 hidden x 4 gates.
// LDS: W_hh slice 64KB + W_ih slice 40KB (both staged once, XOR-swizzled).
// x_t prefetched one step ahead into raw f32 regs (loads fly during poll +
// h-GEMM + publish; cvt f32->f16 deferred to consumption). h exchanged via
// coherence-point relaxed atomics; per-step fetch_add flag per (dir,half)
// group of 32 blocks (R1 scheme - best measured).

__global__ __launch_bounds__(256, 1) void k_phaseA(
    const float* __restrict__ x,
    const f16* __restrict__ w0f, const f16* __restrict__ w0r,
    const f16* __restrict__ whf, const f16* __restrict__ whr,
    const float* __restrict__ bs0, const int* __restrict__ len,
    f16* __restrict__ hxA, f16* __restrict__ outcat,
    u32* __restrict__ barA)
{
  __shared__ f16 Wh[64*512];   // 64 KB
  __shared__ f16 Wi[64*320];   // 40 KB
  const int half = blockIdx.x, jb = blockIdx.y, dir = blockIdx.z;
  const f16* wih = dir ? w0r : w0f;
  const f16* whh = dir ? whr : whf;
  const float* bias = bs0 + dir*G_;
  f16* hx = hxA + (size_t)dir*(2*B_*H_);
  u32* mybar = barA + (dir*2 + half)*S_;
  const int tid = threadIdx.x;
  const int w = tid>>6, lane = tid&63, quad = lane>>4, l16 = lane&15;
  const int j0 = jb*16;
  const int m0 = half*64 + w*16;       // this wave's 16 batch rows

  for (int u = tid; u < 4096; u += 256){
    int lrr = u>>6, uc = u&63;
    int g = lrr>>4, i = lrr&15;
    *(uint4*)&Wh[lrr*512 + (uc ^ (i&7))*8] =
        *(const uint4*)(whh + ((size_t)(g*H_ + j0 + i))*H_ + uc*8);
  }
  // W_ih slice: 64 rows x 40 chunks of 8 f16; chunk XOR-swizzled per row
  for (int u = tid; u < 2560; u += 256){
    int row = u/40, c = u - row*40;
    int g = row>>4, i = row&15;
    *(uint4*)&Wi[row*320 + (c ^ (i&7))*8] =
        *(const uint4*)(wih + ((size_t)(g*H_ + j0 + i))*EP_ + c*8);
  }
  __syncthreads();

  const int j = j0 + l16;
  float bz[4], hprev[4], cpr[4]; int lm[4];
#pragma unroll
  for (int g = 0; g < 4; ++g) bz[g] = bias[g*H_ + j];
#pragma unroll
  for (int r = 0; r < 4; ++r){ hprev[r] = 1.f; cpr[r] = 1.f; lm[r] = len[m0 + quad*4 + r]; }
  const size_t xrowbase = (size_t)(m0 + l16)*S_;

  // --- cross-step x prefetch state (raw f32; cvt deferred to consumption) ---
  float4 xA[9], xB[9]; float xT[8];
  {
    const int t0 = dir ? (S_-1) : 0;
    const float* xr = x + (xrowbase + t0)*E_;
#pragma unroll
    for (int kb = 0; kb < 9; ++kb){
      xA[kb] = *(const float4*)(xr + kb*32 + quad*8);
      xB[kb] = *(const float4*)(xr + kb*32 + quad*8 + 4);
    }
    int kbase = 288 + quad*8;
#pragma unroll
    for (int e2 = 0; e2 < 8; ++e2)
      xT[e2] = (kbase + e2 < E_) ? xr[kbase + e2] : 0.f;
  }

  for (int s = 0; s < S_; ++s){
    const int t = dir ? (S_-1-s) : s;
    f32x4 z4 = {0.f,0.f,0.f,0.f};
    f32x4 acc[4] = {z4,z4,z4,z4};

    // --- x_t @ Wih^T from prefetched regs + LDS weights ---
#pragma unroll
    for (int kb = 0; kb < 9; ++kb){
      f16x8 a;
      a[0]=(f16)xA[kb].x; a[1]=(f16)xA[kb].y; a[2]=(f16)xA[kb].z; a[3]=(f16)xA[kb].w;
      a[4]=(f16)xB[kb].x; a[5]=(f16)xB[kb].y; a[6]=(f16)xB[kb].z; a[7]=(f16)xB[kb].w;
      int c = (kb*4 + quad) ^ (l16 & 7);
#pragma unroll
      for (int g = 0; g < 4; ++g){
        f16x8 b = *(const f16x8*)&Wi[(g*16+l16)*320 + c*8];
        acc[g] = __builtin_amdgcn_mfma_f32_16x16x32_f16(a, b, acc[g],0,0,0);
      }
    }
    { // K tail 288..319 (x zero-padded in regs; weight pad cols are zero)
      f16x8 a;
#pragma unroll
      for (int e2 = 0; e2 < 8; ++e2) a[e2] = (f16)xT[e2];
      int c = (36 + quad) ^ (l16 & 7);
#pragma unroll
      for (int g = 0; g < 4; ++g){
        f16x8 b = *(const f16x8*)&Wi[(g*16+l16)*320 + c*8];
        acc[g] = __builtin_amdgcn_mfma_f32_16x16x32_f16(a, b, acc[g],0,0,0);
      }
    }

    // --- issue next-step x prefetch (overlaps poll + h-GEMM + publish) ---
    if (s+1 < S_){
      const int tn = dir ? (S_-2-s) : (s+1);
      const float* xr = x + (xrowbase + tn)*E_;
#pragma unroll
      for (int kb = 0; kb < 9; ++kb){
        xA[kb] = *(const float4*)(xr + kb*32 + quad*8);
        xB[kb] = *(const float4*)(xr + kb*32 + quad*8 + 4);
      }
      int kbase = 288 + quad*8;
#pragma unroll
      for (int e2 = 0; e2 < 8; ++e2)
        xT[e2] = (kbase + e2 < E_) ? xr[kbase + e2] : 0.f;
    }

    // --- uniform per-wave poll (one broadcast load; waves proceed independently) ---
    if (s > 0){
      while (__hip_atomic_load(&mybar[s-1], __ATOMIC_RELAXED, __HIP_MEMORY_SCOPE_AGENT) < 32u) {}
    }
    asm volatile("" ::: "memory");   // keep h loads below the poll

    // --- h @ Whh^T (K=512): batch-issue ALL 32 coherence-point loads, then MFMA ---
    const int par = s & 1;
    const u64* hap = (const u64*)(hx + (size_t)par*(B_*H_) + (size_t)(m0 + l16)*H_);
    u64 hq[32];
#pragma unroll
    for (int kb = 0; kb < 16; ++kb){
      hq[2*kb]   = aload64(hap + kb*8 + quad*2);
      hq[2*kb+1] = aload64(hap + kb*8 + quad*2 + 1);
    }
#pragma unroll
    for (int kb = 0; kb < 16; ++kb){
      H8 ha;
      ha.q[0] = hq[2*kb];
      ha.q[1] = hq[2*kb+1];
      int uq = kb*4 + quad;
#pragma unroll
      for (int g = 0; g < 4; ++g){
        f16x8 b = *(const f16x8*)&Wh[(g*16+l16)*512 + ((uq ^ (l16&7)))*8];
        acc[g] = __builtin_amdgcn_mfma_f32_16x16x32_f16(ha.v, b, acc[g],0,0,0);
      }
    }

    // --- gates + state update; publish h (packed 4B, even lanes) ---
    f16* hn = hx + (size_t)(1-par)*(B_*H_);
#pragma unroll
    for (int r = 0; r < 4; ++r){
      int m = m0 + quad*4 + r;
      float zi = acc[0][r] + bz[0];
      float zf = acc[1][r] + bz[1];
      float zg = acc[2][r] + bz[2];
      float zo = acc[3][r] + bz[3];
      float ig = sigf(zi), fg = sigf(zf), gg = tanhf_(zg), og = sigf(zo);
      float cnew = fg*cpr[r] + ig*gg;
      float hnew = og*tanhf_(cnew);
      bool mk = t < lm[r];
      float hsel = mk ? hnew : hprev[r];
      cpr[r] = mk ? cnew : cpr[r];
      hprev[r] = hsel;
      FU cv; cv.f = (f16)hsel;
      int other = __shfl_down((int)cv.s, 1);
      if ((l16 & 1) == 0)
        astore32((u32*)(hn + (size_t)m*H_ + j), (u32)cv.s | ((u32)other << 16));
    }
    __syncthreads();   // drains h atomic stores (vmcnt(0) before s_barrier)
    if (tid == 0)
      __hip_atomic_fetch_add(&mybar[s], 1u, __ATOMIC_RELAXED, __HIP_MEMORY_SCOPE_AGENT);

    // --- deferred outcat stores (off the inter-block critical path) ---
#pragma unroll
    for (int r = 0; r < 4; ++r){
      int m = m0 + quad*4 + r;
      FU cv; cv.f = (f16)hprev[r];
      int other = __shfl_down((int)cv.s, 1);
      if ((l16 & 1) == 0)
        *(u32*)(outcat + ((size_t)t*B_ + m)*D1_ + dir*H_ + j) = (u32)cv.s | ((u32)other << 16);
    }
  }
}

// ---------------- phase C recurrence: layer-1 reverse over one CH-step chunk ----------------
// grid (2,32) = 64 blocks. Z1c (x-part + bias) precomputed by dense GEMM -> this
// kernel is only the K=512 h-GEMM + gates. Batch-load h (R5 scheme).

__global__ __launch_bounds__(256, 1) void k_phaseCrec(
    const f16* __restrict__ Z1c, const f16* __restrict__ w1h,
    const int* __restrict__ len,
    f16* __restrict__ hx1, float* __restrict__ cstate, float* __restrict__ h1f,
    u32* __restrict__ barC, int s0, int CH)
{
  __shared__ f16 Wh[64*512];   // 64 KB
  const int half = blockIdx.x, jb = blockIdx.y;
  u32* mybar = barC + half*S_;
  const int tid = threadIdx.x;
  const int w = tid>>6, lane = tid&63, quad = lane>>4, l16 = lane&15;
  const int j0 = jb*16;
  const int m0 = half*64 + w*16;

  for (int u = tid; u < 4096; u += 256){
    int lrr = u>>6, uc = u&63;
    int g = lrr>>4, i = lrr&15;
    *(uint4*)&Wh[lrr*512 + (uc ^ (i&7))*8] =
        *(const uint4*)(w1h + ((size_t)(g*H_ + j0 + i))*H_ + uc*8);
  }
  __syncthreads();

  const int j = j0 + l16;
  float hprev[4], cpr[4]; int lm[4];
#pragma unroll
  for (int r = 0; r < 4; ++r){
    int m = m0 + quad*4 + r;
    lm[r] = len[m];
    cpr[r] = cstate[(size_t)m*H_ + j];
    hprev[r] = (float)hx1[(size_t)(s0 & 1)*(B_*H_) + (size_t)m*H_ + j];
  }

  for (int sl = 0; sl < CH; ++sl){
    const int s = s0 + sl;
    const int t = S_-1-s;
    const int zrow = CH-1-sl;

    // --- prefetch Z rows (h-independent; overlaps the wait) ---
    float zv[4][4];
#pragma unroll
    for (int g = 0; g < 4; ++g)
#pragma unroll
      for (int r = 0; r < 4; ++r)
        zv[g][r] = (float)Z1c[((size_t)zrow*B_ + m0 + quad*4 + r)*G_ + g*H_ + j];

    if (s > 0){
      while (__hip_atomic_load(&mybar[s-1], __ATOMIC_RELAXED, __HIP_MEMORY_SCOPE_AGENT) < 32u) {}
    }
    asm volatile("" ::: "memory");

    // --- h @ Whh1^T (K=512): batch-issue loads, then MFMA ---
    const int par = s & 1;
    const u64* hap = (const u64*)(hx1 + (size_t)par*(B_*H_) + (size_t)(m0 + l16)*H_);
    f32x4 z4 = {0.f,0.f,0.f,0.f};
    f32x4 acc[4] = {z4,z4,z4,z4};
    u64 hq[32];
#pragma unroll
    for (int kb = 0; kb < 16; ++kb){
      hq[2*kb]   = aload64(hap + kb*8 + quad*2);
      hq[2*kb+1] = aload64(hap + kb*8 + quad*2 + 1);
    }
#pragma unroll
    for (int kb = 0; kb < 16; ++kb){
      H8 ha;
      ha.q[0] = hq[2*kb];
      ha.q[1] = hq[2*kb+1];
      int uq = kb*4 + quad;
#pragma unroll
      for (int g = 0; g < 4; ++g){
        f16x8 b = *(const f16x8*)&Wh[(g*16+l16)*512 + ((uq ^ (l16&7)))*8];
        acc[g] = __builtin_amdgcn_mfma_f32_16x16x32_f16(ha.v, b, acc[g],0,0,0);
      }
    }

    f16* hn = hx1 + (size_t)(1-par)*(B_*H_);
#pragma unroll
    for (int r = 0; r < 4; ++r){
      int m = m0 + quad*4 + r;
      float zi = acc[0][r] + zv[0][r];
      float zf = acc[1][r] + zv[1][r];
      float zg = acc[2][r] + zv[2][r];
      float zo = acc[3][r] + zv[3][r];
      float ig = sigf(zi), fg = sigf(zf), gg = tanhf_(zg), og = sigf(zo);
      float cnew = fg*cpr[r] + ig*gg;
      float hnew = og*tanhf_(cnew);
      bool mk = t < lm[r];
      float hsel = mk ? hnew : hprev[r];
      cpr[r] = mk ? cnew : cpr[r];
      hprev[r] = hsel;
      FU cv; cv.f = (f16)hsel;
      int other = __shfl_down((int)cv.s, 1);
      if ((l16 & 1) == 0)
        astore32((u32*)(hn + (size_t)m*H_ + j), (u32)cv.s | ((u32)other << 16));
    }
    __syncthreads();
    if (tid == 0)
      __hip_atomic_fetch_add(&mybar[s], 1u, __ATOMIC_RELAXED, __HIP_MEMORY_SCOPE_AGENT);

    if (t == 0){  // deferred final-state write (consumed by k_final after kernel end)
#pragma unroll
      for (int r = 0; r < 4; ++r)
        h1f[(size_t)(m0 + quad*4 + r)*H_ + j] = hprev[r];
    }
  }

  // persist c across chunk launches (h lives in hx1 parity buffers)
#pragma unroll
  for (int r = 0; r < 4; ++r)
    cstate[(size_t)(m0 + quad*4 + r)*H_ + j] = cpr[r];
}

// ---------------- epilogue: folded FC ----------------

__global__ void k_fold(const float* __restrict__ fc1w, const float* __restrict__ fc1b,
                       const float* __restrict__ fcw,  const float* __restrict__ fcb,
                       float* __restrict__ Mf, float* __restrict__ bf){
  int i = blockIdx.x*blockDim.x + threadIdx.x;
  if (i >= 1024) return;
  int o = i >> 9, h = i & 511;
  float s = 0.f;
  for (int jj = 0; jj < 512; ++jj) s += fcw[o*512 + jj] * fc1w[jj*512 + h];
  Mf[o*512 + h] = s;
  if (h == 0){
    float sb = fcb[o];
    for (int jj = 0; jj < 512; ++jj) sb += fcw[o*512 + jj] * fc1b[jj];
    bf[o] = sb;
  }
}

__global__ void k_final(const float* __restrict__ h1f, const float* __restrict__ Mf,
                        const float* __restrict__ bf, float* __restrict__ out){
  int i = threadIdx.x;
  if (i >= 256) return;
  int b = i >> 1, o = i & 1;
  float s = bf[o];
  const float* hp = h1f + (size_t)b*512;
  const float* mp = Mf + (size_t)o*512;
  for (int h = 0; h < 512; ++h) s += hp[h]*mp[h];
  out[b*2 + o] = s;
}

// ---------------- host ----------------

extern "C" void kernel_launch(void* const* d_in, const int* in_sizes, int n_in,
                              void* d_out, int out_size, void* d_ws, size_t ws_size,
                              hipStream_t stream)
{
  const float* x     = (const float*)d_in[0];
  const float* wih0f = (const float*)d_in[1];
  const float* whh0f = (const float*)d_in[2];
  const float* bih0f = (const float*)d_in[3];
  const float* bhh0f = (const float*)d_in[4];
  const float* wih0r = (const float*)d_in[5];
  const float* whh0r = (const float*)d_in[6];
  const float* bih0r = (const float*)d_in[7];
  const float* bhh0r = (const float*)d_in[8];
  // d_in[9..12] = layer1 forward: dead code (only hT_r of layer1 reaches output)
  const float* wih1r = (const float*)d_in[13];
  const float* whh1r = (const float*)d_in[14];
  const float* bih1r = (const float*)d_in[15];
  const float* bhh1r = (const float*)d_in[16];
  const float* fc1w  = (const float*)d_in[17];
  const float* fc1b  = (const float*)d_in[18];
  const float* fcw   = (const float*)d_in[19];
  const float* fcb   = (const float*)d_in[20];
  float* out = (float*)d_out;

  char* p = (char*)d_ws;
  auto alloc = [&](size_t bytes)->char*{
    char* r = p; p += (bytes + 255) & ~(size_t)255; return r;
  };
  f16* w0fp   = (f16*)alloc((size_t)G_*EP_*2);       // 1.3 MB
  f16* w0rp   = (f16*)alloc((size_t)G_*EP_*2);
  f16* whf    = (f16*)alloc((size_t)G_*H_*2);        // 2 MB
  f16* whr    = (f16*)alloc((size_t)G_*H_*2);
  f16* w1i    = (f16*)alloc((size_t)G_*D1_*2);       // 4 MB
  f16* w1h    = (f16*)alloc((size_t)G_*H_*2);        // 2 MB
  float* bs0  = (float*)alloc((size_t)2*G_*4);
  float* bs1r = (float*)alloc(G_*4);
  int*   len  = (int*)alloc(B_*4);
  f16* outcat = (f16*)alloc((size_t)S_*B_*D1_*2);    // 67 MB
  f16* hxA    = (f16*)alloc((size_t)2*2*B_*H_*2);
  f16* hx1    = (f16*)alloc((size_t)2*B_*H_*2);
  float* cstate=(float*)alloc((size_t)B_*H_*4);
  float* h1f  = (float*)alloc((size_t)B_*H_*4);
  float* Mf   = (float*)alloc(2*512*4);
  float* bf   = (float*)alloc(256);
  u32* barA   = (u32*)alloc(4*S_*4);
  u32* barC   = (u32*)alloc(2*S_*4);
  // fixed ~81 MB; Z1c chunk adaptive
  size_t used = (size_t)(p - (char*)d_ws);
  int CH = 8;
  for (int c = 256; c >= 8; c >>= 1){
    if (used + (size_t)c*B_*G_*2 <= ws_size){ CH = c; break; }
  }
  f16* Z1c = (f16*)alloc((size_t)CH*B_*G_*2);
  const int NC = S_/CH;

  int n;
  n = G_*EP_; k_pad_w<<<(n+255)/256, 256, 0, stream>>>(wih0f, w0fp, G_, E_, EP_);
              k_pad_w<<<(n+255)/256, 256, 0, stream>>>(wih0r, w0rp, G_, E_, EP_);
  n = G_*H_;  k_f32_to_f16<<<(n+255)/256,256,0,stream>>>(whh0f, whf, n);
              k_f32_to_f16<<<(n+255)/256,256,0,stream>>>(whh0r, whr, n);
              k_f32_to_f16<<<(n+255)/256,256,0,stream>>>(whh1r, w1h, n);
  n = G_*D1_; k_f32_to_f16<<<(n+255)/256,256,0,stream>>>(wih1r, w1i, n);
  k_bias<<<8,256,0,stream>>>(bih0f, bhh0f, bs0, G_);
  k_bias<<<8,256,0,stream>>>(bih0r, bhh0r, bs0 + G_, G_);
  k_bias<<<8,256,0,stream>>>(bih1r, bhh1r, bs1r, G_);
  k_len<<<1,128,0,stream>>>(x, len);
  k_init<<<(B_*H_+255)/256,256,0,stream>>>(hxA, hx1, cstate, barA, barC);
  k_fold<<<4,256,0,stream>>>(fc1w, fc1b, fcw, fcb, Mf, bf);

  // ---- phase A: layer-0 fwd+rev, single persistent launch ----
  k_phaseA<<<dim3(2,32,2), 256, 0, stream>>>(
      x, w0fp, w0rp, whf, whr, bs0, len, hxA, outcat, barA);

  // ---- phase C: per chunk, dense Z1 GEMM then recurrence ----
  for (int cc = 0; cc < NC; ++cc){
    int t0 = S_ - (cc+1)*CH;     // chunk covers t in [t0, t0+CH), consumed descending
    k_gemm_bt<<<dim3(CH*2,32), 256, 0, stream>>>(
        outcat + (size_t)t0*B_*D1_, w1i, Z1c, bs1r, CH*B_, G_, D1_);
    k_phaseCrec<<<dim3(2,32), 256, 0, stream>>>(
        Z1c, w1h, len, hx1, cstate, h1f, barC, cc*CH, CH);
  }

  k_final<<<1,256,0,stream>>>(h1f, Mf, bf, out);
}

// Round 8
// 4107.837 us; speedup vs baseline: 1.6555x; 1.0412x over previous
//
#include <hip/hip_runtime.h>

#define B_  128
#define S_  256
#define E_  300
#define EP_ 320
#define H_  512
#define G_  2048   // 4*H
#define D1_ 1024   // 2*H
// padded flags: [grp][slot(4)][wave(4)][jb(32)] x 32 u32 (128B line each)
#define FSLOT_ 4
#define FA_WORDS_ (4*FSLOT_*4*32*32)
#define FC_WORDS_ (2*FSLOT_*4*32*32)

typedef _Float16 f16;
typedef __attribute__((ext_vector_type(8))) _Float16 f16x8;
typedef __attribute__((ext_vector_type(4))) float    f32x4;
typedef unsigned long long u64;
typedef unsigned int u32;

__device__ __forceinline__ float sigf(float x){ return 1.f/(1.f + __expf(-x)); }
__device__ __forceinline__ float tanhf_(float x){
  float e = __expf(-2.f*fabsf(x));
  float t = (1.f - e)/(1.f + e);
  return x < 0.f ? -t : t;
}

// Relaxed agent-scope atomics route to the coherence point, bypassing the
// non-coherent per-XCD L2s.
// Ledger: R1 fetch_add 11.0us/step; R2 write-once same-line flags 12.2; R4
// tagged-data 14.2; R5 batch h-loads 10.35; R7 Wi->LDS + x-reg-prefetch 8.8.
// Execution is ~0.9us/step (MfmaUtil 4%) -> ~7.9us residual. All prior sync
// schemes funneled 32 producers into ONE cache line per step (R1: one word;
// R2: 32 consecutive words = same 128B line) -> serialized line ownership at
// the coherence point ~= the residual. R8: write-once flags PADDED to one
// 128B line per (wave,jb), value-encoded (s+1) with a 4-slot window; producer
// drains own stores (vmcnt(0)) then stores flag; consumer gathers 32 flags
// (32 distinct lines, one 32-lane load) + ballot. No syncthreads, no RMW.
__device__ __forceinline__ u64 aload64(const u64* p){
  return __hip_atomic_load((u64*)p, __ATOMIC_RELAXED, __HIP_MEMORY_SCOPE_AGENT);
}
__device__ __forceinline__ u32 aload32(const u32* p){
  return __hip_atomic_load((u32*)p, __ATOMIC_RELAXED, __HIP_MEMORY_SCOPE_AGENT);
}
__device__ __forceinline__ void astore32(u32* p, u32 v){
  __hip_atomic_store(p, v, __ATOMIC_RELAXED, __HIP_MEMORY_SCOPE_AGENT);
}
union H8 { u64 q[2]; f16x8 v; };
union FU { f16 f; unsigned short s; };

// ---------------- setup kernels ----------------

__global__ void k_f32_to_f16(const float* __restrict__ s, f16* __restrict__ d, int n){
  int i = blockIdx.x*blockDim.x + threadIdx.x;
  if (i < n) d[i] = (f16)s[i];
}

__global__ void k_pad_w(const float* __restrict__ s, f16* __restrict__ d, int rows, int ks, int kd){
  int i = blockIdx.x*blockDim.x + threadIdx.x;
  if (i >= rows*kd) return;
  int r = i/kd, k = i - r*kd;
  d[i] = (k < ks) ? (f16)s[(size_t)r*ks + k] : (f16)0.f;
}

__global__ void k_bias(const float* __restrict__ a, const float* __restrict__ b,
                       float* __restrict__ d, int n){
  int i = blockIdx.x*blockDim.x + threadIdx.x;
  if (i < n) d[i] = a[i] + b[i];
}

__global__ void k_len(const float* __restrict__ x, int* __restrict__ len){
  int b = threadIdx.x;
  if (b < B_){
    int v = (int)x[((size_t)b*S_ + (S_-1))*E_];
    len[b] = v > S_ ? S_ : v;
  }
}

__global__ void k_zero(u32* __restrict__ p, int n){
  int i = blockIdx.x*blockDim.x + threadIdx.x;
  if (i < n) p[i] = 0u;
}

// hxA: [dir][parity][B*H], hx1: [parity][B*H]; parity-0 = h0 = 1. cstate = c0 = 1.
__global__ void k_init(f16* hxA, f16* hx1, float* cstate){
  int i = blockIdx.x*blockDim.x + threadIdx.x;
  if (i < B_*H_){
    hxA[i] = (f16)1.f;                // dir0 par0
    hxA[2*B_*H_ + i] = (f16)1.f;      // dir1 par0
    hx1[i] = (f16)1.f;                // par0
    cstate[i] = 1.f;
  }
}

// ---------------- GEMM: C[M,N] = A[M,K] @ B[N,K]^T + bias (f16 in/out, fp32 acc) ----------------

__global__ __launch_bounds__(256) void k_gemm_bt(
    const f16* __restrict__ A, const f16* __restrict__ Bm,
    f16* __restrict__ C, const float* __restrict__ bias,
    int M, int N, int K)
{
  __shared__ f16 As[64*40];
  __shared__ f16 Bs[64*40];
  const int m0 = blockIdx.x*64, n0 = blockIdx.y*64;
  const int tid = threadIdx.x;
  const int w = tid>>6, lane = tid&63, quad = lane>>4, l16 = lane&15;
  const int wm = (w&1)*32, wn = (w>>1)*32;
  const int lr = tid>>2, lc = (tid&3)*8;
  const f16* Ap = A + (size_t)(m0+lr)*K + lc;
  const f16* Bp = Bm + (size_t)(n0+lr)*K + lc;
  f32x4 z4 = {0.f,0.f,0.f,0.f};
  f32x4 acc[2][2] = {{z4,z4},{z4,z4}};
  for (int k0 = 0; k0 < K; k0 += 32){
    *(uint4*)&As[lr*40+lc] = *(const uint4*)(Ap + k0);
    *(uint4*)&Bs[lr*40+lc] = *(const uint4*)(Bp + k0);
    __syncthreads();
    f16x8 a0 = *(const f16x8*)&As[(wm+l16)*40 + quad*8];
    f16x8 a1 = *(const f16x8*)&As[(wm+16+l16)*40 + quad*8];
    f16x8 b0 = *(const f16x8*)&Bs[(wn+l16)*40 + quad*8];
    f16x8 b1 = *(const f16x8*)&Bs[(wn+16+l16)*40 + quad*8];
    acc[0][0] = __builtin_amdgcn_mfma_f32_16x16x32_f16(a0,b0,acc[0][0],0,0,0);
    acc[0][1] = __builtin_amdgcn_mfma_f32_16x16x32_f16(a0,b1,acc[0][1],0,0,0);
    acc[1][0] = __builtin_amdgcn_mfma_f32_16x16x32_f16(a1,b0,acc[1][0],0,0,0);
    acc[1][1] = __builtin_amdgcn_mfma_f32_16x16x32_f16(a1,b1,acc[1][1],0,0,0);
    __syncthreads();
  }
#pragma unroll
  for (int mi = 0; mi < 2; ++mi)
#pragma unroll
    for (int ni = 0; ni < 2; ++ni){
      int col = n0 + wn + ni*16 + l16;
      float bz = bias[col];
#pragma unroll
      for (int r = 0; r < 4; ++r){
        int row = m0 + wm + mi*16 + quad*4 + r;
        C[(size_t)row*N + col] = (f16)(acc[mi][ni][r] + bz);
      }
    }
}

// ---------------- phase A: persistent layer-0 fwd+rev, column-partitioned ----------------
// grid (2,32,2) = 128 blocks, 256 thr. Block: 64 batch rows x 16 hidden x 4 gates.
// LDS: W_hh 64KB + W_ih 40KB (staged once, XOR-swizzled). x_t prefetched one
// step ahead into raw f32 regs. h exchanged via coherence-point relaxed
// atomics. Sync (R8): per-(wave,jb) write-once flag on its OWN 128B line,
// value s+1, slot window 4; producer: vmcnt(0) then lane0 flag store;
// consumer: 32-lane gather of 32 lines + ballot. No syncthreads, no RMW.

__global__ __launch_bounds__(256, 1) void k_phaseA(
    const float* __restrict__ x,
    const f16* __restrict__ w0f, const f16* __restrict__ w0r,
    const f16* __restrict__ whf, const f16* __restrict__ whr,
    const float* __restrict__ bs0, const int* __restrict__ len,
    f16* __restrict__ hxA, f16* __restrict__ outcat,
    u32* __restrict__ flagsA)
{
  __shared__ f16 Wh[64*512];   // 64 KB
  __shared__ f16 Wi[64*320];   // 40 KB
  const int half = blockIdx.x, jb = blockIdx.y, dir = blockIdx.z;
  const f16* wih = dir ? w0r : w0f;
  const f16* whh = dir ? whr : whf;
  const float* bias = bs0 + dir*G_;
  f16* hx = hxA + (size_t)dir*(2*B_*H_);
  u32* fbase = flagsA + (size_t)(dir*2 + half)*(FSLOT_*4*32*32);
  const int tid = threadIdx.x;
  const int w = tid>>6, lane = tid&63, quad = lane>>4, l16 = lane&15;
  const int j0 = jb*16;
  const int m0 = half*64 + w*16;       // this wave's 16 batch rows

  for (int u = tid; u < 4096; u += 256){
    int lrr = u>>6, uc = u&63;
    int g = lrr>>4, i = lrr&15;
    *(uint4*)&Wh[lrr*512 + (uc ^ (i&7))*8] =
        *(const uint4*)(whh + ((size_t)(g*H_ + j0 + i))*H_ + uc*8);
  }
  // W_ih slice: 64 rows x 40 chunks of 8 f16; chunk XOR-swizzled per row
  for (int u = tid; u < 2560; u += 256){
    int row = u/40, c = u - row*40;
    int g = row>>4, i = row&15;
    *(uint4*)&Wi[row*320 + (c ^ (i&7))*8] =
        *(const uint4*)(wih + ((size_t)(g*H_ + j0 + i))*EP_ + c*8);
  }
  __syncthreads();

  const int j = j0 + l16;
  float bz[4], hprev[4], cpr[4]; int lm[4];
#pragma unroll
  for (int g = 0; g < 4; ++g) bz[g] = bias[g*H_ + j];
#pragma unroll
  for (int r = 0; r < 4; ++r){ hprev[r] = 1.f; cpr[r] = 1.f; lm[r] = len[m0 + quad*4 + r]; }
  const size_t xrowbase = (size_t)(m0 + l16)*S_;

  // --- cross-step x prefetch state (raw f32; cvt deferred to consumption) ---
  float4 xA[9], xB[9]; float xT[8];
  {
    const int t0 = dir ? (S_-1) : 0;
    const float* xr = x + (xrowbase + t0)*E_;
#pragma unroll
    for (int kb = 0; kb < 9; ++kb){
      xA[kb] = *(const float4*)(xr + kb*32 + quad*8);
      xB[kb] = *(const float4*)(xr + kb*32 + quad*8 + 4);
    }
    int kbase = 288 + quad*8;
#pragma unroll
    for (int e2 = 0; e2 < 8; ++e2)
      xT[e2] = (kbase + e2 < E_) ? xr[kbase + e2] : 0.f;
  }

  for (int s = 0; s < S_; ++s){
    const int t = dir ? (S_-1-s) : s;
    f32x4 z4 = {0.f,0.f,0.f,0.f};
    f32x4 acc[4] = {z4,z4,z4,z4};

    // --- x_t @ Wih^T from prefetched regs + LDS weights ---
#pragma unroll
    for (int kb = 0; kb < 9; ++kb){
      f16x8 a;
      a[0]=(f16)xA[kb].x; a[1]=(f16)xA[kb].y; a[2]=(f16)xA[kb].z; a[3]=(f16)xA[kb].w;
      a[4]=(f16)xB[kb].x; a[5]=(f16)xB[kb].y; a[6]=(f16)xB[kb].z; a[7]=(f16)xB[kb].w;
      int c = (kb*4 + quad) ^ (l16 & 7);
#pragma unroll
      for (int g = 0; g < 4; ++g){
        f16x8 b = *(const f16x8*)&Wi[(g*16+l16)*320 + c*8];
        acc[g] = __builtin_amdgcn_mfma_f32_16x16x32_f16(a, b, acc[g],0,0,0);
      }
    }
    { // K tail 288..319 (x zero-padded in regs; weight pad cols are zero)
      f16x8 a;
#pragma unroll
      for (int e2 = 0; e2 < 8; ++e2) a[e2] = (f16)xT[e2];
      int c = (36 + quad) ^ (l16 & 7);
#pragma unroll
      for (int g = 0; g < 4; ++g){
        f16x8 b = *(const f16x8*)&Wi[(g*16+l16)*320 + c*8];
        acc[g] = __builtin_amdgcn_mfma_f32_16x16x32_f16(a, b, acc[g],0,0,0);
      }
    }

    // --- issue next-step x prefetch (overlaps poll + h-GEMM + publish) ---
    if (s+1 < S_){
      const int tn = dir ? (S_-2-s) : (s+1);
      const float* xr = x + (xrowbase + tn)*E_;
#pragma unroll
      for (int kb = 0; kb < 9; ++kb){
        xA[kb] = *(const float4*)(xr + kb*32 + quad*8);
        xB[kb] = *(const float4*)(xr + kb*32 + quad*8 + 4);
      }
      int kbase = 288 + quad*8;
#pragma unroll
      for (int e2 = 0; e2 < 8; ++e2)
        xT[e2] = (kbase + e2 < E_) ? xr[kbase + e2] : 0.f;
    }

    // --- poll: 32 padded flags (32 distinct lines), one gather + ballot ---
    if (s > 0){
      const u32* fp = fbase + ((size_t)((s-1)&(FSLOT_-1))*4 + w)*32*32;
      const u32 expv = (u32)s;
      for (;;){
        u32 v = aload32(fp + (size_t)(lane & 31)*32);
        if (__ballot(v == expv) == ~0ull) break;
      }
      asm volatile("" ::: "memory");   // keep h loads below the poll
    }

    // --- h @ Whh^T (K=512): batch-issue ALL 32 coherence-point loads, then MFMA ---
    const int par = s & 1;
    const u64* hap = (const u64*)(hx + (size_t)par*(B_*H_) + (size_t)(m0 + l16)*H_);
    u64 hq[32];
#pragma unroll
    for (int kb = 0; kb < 16; ++kb){
      hq[2*kb]   = aload64(hap + kb*8 + quad*2);
      hq[2*kb+1] = aload64(hap + kb*8 + quad*2 + 1);
    }
#pragma unroll
    for (int kb = 0; kb < 16; ++kb){
      H8 ha;
      ha.q[0] = hq[2*kb];
      ha.q[1] = hq[2*kb+1];
      int uq = kb*4 + quad;
#pragma unroll
      for (int g = 0; g < 4; ++g){
        f16x8 b = *(const f16x8*)&Wh[(g*16+l16)*512 + ((uq ^ (l16&7)))*8];
        acc[g] = __builtin_amdgcn_mfma_f32_16x16x32_f16(ha.v, b, acc[g],0,0,0);
      }
    }

    // --- gates + state update; publish h (packed 4B, even lanes) ---
    f16* hn = hx + (size_t)(1-par)*(B_*H_);
#pragma unroll
    for (int r = 0; r < 4; ++r){
      int m = m0 + quad*4 + r;
      float zi = acc[0][r] + bz[0];
      float zf = acc[1][r] + bz[1];
      float zg = acc[2][r] + bz[2];
      float zo = acc[3][r] + bz[3];
      float ig = sigf(zi), fg = sigf(zf), gg = tanhf_(zg), og = sigf(zo);
      float cnew = fg*cpr[r] + ig*gg;
      float hnew = og*tanhf_(cnew);
      bool mk = t < lm[r];
      float hsel = mk ? hnew : hprev[r];
      cpr[r] = mk ? cnew : cpr[r];
      hprev[r] = hsel;
      FU cv; cv.f = (f16)hsel;
      int other = __shfl_down((int)cv.s, 1);
      if ((l16 & 1) == 0)
        astore32((u32*)(hn + (size_t)m*H_ + j), (u32)cv.s | ((u32)other << 16));
    }
    // per-wave drain (covers this wave's h stores AND its old-parity reads),
    // then write-once flag on this (wave,jb)'s private 128B line
    asm volatile("s_waitcnt vmcnt(0)" ::: "memory");
    if (lane == 0)
      astore32(fbase + (((size_t)(s&(FSLOT_-1))*4 + w)*32 + jb)*32, (u32)(s+1));

    // --- deferred outcat stores (off the inter-block critical path) ---
#pragma unroll
    for (int r = 0; r < 4; ++r){
      int m = m0 + quad*4 + r;
      FU cv; cv.f = (f16)hprev[r];
      int other = __shfl_down((int)cv.s, 1);
      if ((l16 & 1) == 0)
        *(u32*)(outcat + ((size_t)t*B_ + m)*D1_ + dir*H_ + j) = (u32)cv.s | ((u32)other << 16);
    }
  }
}

// ---------------- phase C recurrence: layer-1 reverse over one CH-step chunk ----------------
// grid (2,32) = 64 blocks. Same padded-flag scheme; s is global across chunk
// launches (flags persist; window 4 >> max skew 2).

__global__ __launch_bounds__(256, 1) void k_phaseCrec(
    const f16* __restrict__ Z1c, const f16* __restrict__ w1h,
    const int* __restrict__ len,
    f16* __restrict__ hx1, float* __restrict__ cstate, float* __restrict__ h1f,
    u32* __restrict__ flagsC, int s0, int CH)
{
  __shared__ f16 Wh[64*512];   // 64 KB
  const int half = blockIdx.x, jb = blockIdx.y;
  u32* fbase = flagsC + (size_t)half*(FSLOT_*4*32*32);
  const int tid = threadIdx.x;
  const int w = tid>>6, lane = tid&63, quad = lane>>4, l16 = lane&15;
  const int j0 = jb*16;
  const int m0 = half*64 + w*16;

  for (int u = tid; u < 4096; u += 256){
    int lrr = u>>6, uc = u&63;
    int g = lrr>>4, i = lrr&15;
    *(uint4*)&Wh[lrr*512 + (uc ^ (i&7))*8] =
        *(const uint4*)(w1h + ((size_t)(g*H_ + j0 + i))*H_ + uc*8);
  }
  __syncthreads();

  const int j = j0 + l16;
  float hprev[4], cpr[4]; int lm[4];
#pragma unroll
  for (int r = 0; r < 4; ++r){
    int m = m0 + quad*4 + r;
    lm[r] = len[m];
    cpr[r] = cstate[(size_t)m*H_ + j];
    hprev[r] = (float)hx1[(size_t)(s0 & 1)*(B_*H_) + (size_t)m*H_ + j];
  }

  for (int sl = 0; sl < CH; ++sl){
    const int s = s0 + sl;
    const int t = S_-1-s;
    const int zrow = CH-1-sl;

    // --- prefetch Z rows (h-independent; overlaps the wait) ---
    float zv[4][4];
#pragma unroll
    for (int g = 0; g < 4; ++g)
#pragma unroll
      for (int r = 0; r < 4; ++r)
        zv[g][r] = (float)Z1c[((size_t)zrow*B_ + m0 + quad*4 + r)*G_ + g*H_ + j];

    if (s > 0){
      const u32* fp = fbase + ((size_t)((s-1)&(FSLOT_-1))*4 + w)*32*32;
      const u32 expv = (u32)s;
      for (;;){
        u32 v = aload32(fp + (size_t)(lane & 31)*32);
        if (__ballot(v == expv) == ~0ull) break;
      }
      asm volatile("" ::: "memory");
    }

    // --- h @ Whh1^T (K=512): batch-issue loads, then MFMA ---
    const int par = s & 1;
    const u64* hap = (const u64*)(hx1 + (size_t)par*(B_*H_) + (size_t)(m0 + l16)*H_);
    f32x4 z4 = {0.f,0.f,0.f,0.f};
    f32x4 acc[4] = {z4,z4,z4,z4};
    u64 hq[32];
#pragma unroll
    for (int kb = 0; kb < 16; ++kb){
      hq[2*kb]   = aload64(hap + kb*8 + quad*2);
      hq[2*kb+1] = aload64(hap + kb*8 + quad*2 + 1);
    }
#pragma unroll
    for (int kb = 0; kb < 16; ++kb){
      H8 ha;
      ha.q[0] = hq[2*kb];
      ha.q[1] = hq[2*kb+1];
      int uq = kb*4 + quad;
#pragma unroll
      for (int g = 0; g < 4; ++g){
        f16x8 b = *(const f16x8*)&Wh[(g*16+l16)*512 + ((uq ^ (l16&7)))*8];
        acc[g] = __builtin_amdgcn_mfma_f32_16x16x32_f16(ha.v, b, acc[g],0,0,0);
      }
    }

    f16* hn = hx1 + (size_t)(1-par)*(B_*H_);
#pragma unroll
    for (int r = 0; r < 4; ++r){
      int m = m0 + quad*4 + r;
      float zi = acc[0][r] + zv[0][r];
      float zf = acc[1][r] + zv[1][r];
      float zg = acc[2][r] + zv[2][r];
      float zo = acc[3][r] + zv[3][r];
      float ig = sigf(zi), fg = sigf(zf), gg = tanhf_(zg), og = sigf(zo);
      float cnew = fg*cpr[r] + ig*gg;
      float hnew = og*tanhf_(cnew);
      bool mk = t < lm[r];
      float hsel = mk ? hnew : hprev[r];
      cpr[r] = mk ? cnew : cpr[r];
      hprev[r] = hsel;
      FU cv; cv.f = (f16)hsel;
      int other = __shfl_down((int)cv.s, 1);
      if ((l16 & 1) == 0)
        astore32((u32*)(hn + (size_t)m*H_ + j), (u32)cv.s | ((u32)other << 16));
    }
    asm volatile("s_waitcnt vmcnt(0)" ::: "memory");
    if (lane == 0)
      astore32(fbase + (((size_t)(s&(FSLOT_-1))*4 + w)*32 + jb)*32, (u32)(s+1));

    if (t == 0){  // deferred final-state write (consumed by k_final after kernel end)
#pragma unroll
      for (int r = 0; r < 4; ++r)
        h1f[(size_t)(m0 + quad*4 + r)*H_ + j] = hprev[r];
    }
  }

  // persist c across chunk launches (h lives in hx1 parity buffers)
#pragma unroll
  for (int r = 0; r < 4; ++r)
    cstate[(size_t)(m0 + quad*4 + r)*H_ + j] = cpr[r];
}

// ---------------- epilogue: folded FC ----------------

__global__ void k_fold(const float* __restrict__ fc1w, const float* __restrict__ fc1b,
                       const float* __restrict__ fcw,  const float* __restrict__ fcb,
                       float* __restrict__ Mf, float* __restrict__ bf){
  int i = blockIdx.x*blockDim.x + threadIdx.x;
  if (i >= 1024) return;
  int o = i >> 9, h = i & 511;
  float s = 0.f;
  for (int jj = 0; jj < 512; ++jj) s += fcw[o*512 + jj] * fc1w[jj*512 + h];
  Mf[o*512 + h] = s;
  if (h == 0){
    float sb = fcb[o];
    for (int jj = 0; jj < 512; ++jj) sb += fcw[o*512 + jj] * fc1b[jj];
    bf[o] = sb;
  }
}

__global__ void k_final(const float* __restrict__ h1f, const float* __restrict__ Mf,
                        const float* __restrict__ bf, float* __restrict__ out){
  int i = threadIdx.x;
  if (i >= 256) return;
  int b = i >> 1, o = i & 1;
  float s = bf[o];
  const float* hp = h1f + (size_t)b*512;
  const float* mp = Mf + (size_t)o*512;
  for (int h = 0; h < 512; ++h) s += hp[h]*mp[h];
  out[b*2 + o] = s;
}

// ---------------- host ----------------

extern "C" void kernel_launch(void* const* d_in, const int* in_sizes, int n_in,
                              void* d_out, int out_size, void* d_ws, size_t ws_size,
                              hipStream_t stream)
{
  const float* x     = (const float*)d_in[0];
  const float* wih0f = (const float*)d_in[1];
  const float* whh0f = (const float*)d_in[2];
  const float* bih0f = (const float*)d_in[3];
  const float* bhh0f = (const float*)d_in[4];
  const float* wih0r = (const float*)d_in[5];
  const float* whh0r = (const float*)d_in[6];
  const float* bih0r = (const float*)d_in[7];
  const float* bhh0r = (const float*)d_in[8];
  // d_in[9..12] = layer1 forward: dead code (only hT_r of layer1 reaches output)
  const float* wih1r = (const float*)d_in[13];
  const float* whh1r = (const float*)d_in[14];
  const float* bih1r = (const float*)d_in[15];
  const float* bhh1r = (const float*)d_in[16];
  const float* fc1w  = (const float*)d_in[17];
  const float* fc1b  = (const float*)d_in[18];
  const float* fcw   = (const float*)d_in[19];
  const float* fcb   = (const float*)d_in[20];
  float* out = (float*)d_out;

  char* p = (char*)d_ws;
  auto alloc = [&](size_t bytes)->char*{
    char* r = p; p += (bytes + 255) & ~(size_t)255; return r;
  };
  f16* w0fp   = (f16*)alloc((size_t)G_*EP_*2);       // 1.3 MB
  f16* w0rp   = (f16*)alloc((size_t)G_*EP_*2);
  f16* whf    = (f16*)alloc((size_t)G_*H_*2);        // 2 MB
  f16* whr    = (f16*)alloc((size_t)G_*H_*2);
  f16* w1i    = (f16*)alloc((size_t)G_*D1_*2);       // 4 MB
  f16* w1h    = (f16*)alloc((size_t)G_*H_*2);        // 2 MB
  float* bs0  = (float*)alloc((size_t)2*G_*4);
  float* bs1r = (float*)alloc(G_*4);
  int*   len  = (int*)alloc(B_*4);
  f16* outcat = (f16*)alloc((size_t)S_*B_*D1_*2);    // 67 MB
  f16* hxA    = (f16*)alloc((size_t)2*2*B_*H_*2);
  f16* hx1    = (f16*)alloc((size_t)2*B_*H_*2);
  float* cstate=(float*)alloc((size_t)B_*H_*4);
  float* h1f  = (float*)alloc((size_t)B_*H_*4);
  float* Mf   = (float*)alloc(2*512*4);
  float* bf   = (float*)alloc(256);
  u32* flagsA = (u32*)alloc((size_t)FA_WORDS_*4);    // 256 KB padded flags
  u32* flagsC = (u32*)alloc((size_t)FC_WORDS_*4);    // 128 KB
  // fixed ~82 MB; Z1c chunk adaptive
  size_t used = (size_t)(p - (char*)d_ws);
  int CH = 8;
  for (int c = 256; c >= 8; c >>= 1){
    if (used + (size_t)c*B_*G_*2 <= ws_size){ CH = c; break; }
  }
  f16* Z1c = (f16*)alloc((size_t)CH*B_*G_*2);
  const int NC = S_/CH;

  int n;
  n = G_*EP_; k_pad_w<<<(n+255)/256, 256, 0, stream>>>(wih0f, w0fp, G_, E_, EP_);
              k_pad_w<<<(n+255)/256, 256, 0, stream>>>(wih0r, w0rp, G_, E_, EP_);
  n = G_*H_;  k_f32_to_f16<<<(n+255)/256,256,0,stream>>>(whh0f, whf, n);
              k_f32_to_f16<<<(n+255)/256,256,0,stream>>>(whh0r, whr, n);
              k_f32_to_f16<<<(n+255)/256,256,0,stream>>>(whh1r, w1h, n);
  n = G_*D1_; k_f32_to_f16<<<(n+255)/256,256,0,stream>>>(wih1r, w1i, n);
  k_bias<<<8,256,0,stream>>>(bih0f, bhh0f, bs0, G_);
  k_bias<<<8,256,0,stream>>>(bih0r, bhh0r, bs0 + G_, G_);
  k_bias<<<8,256,0,stream>>>(bih1r, bhh1r, bs1r, G_);
  k_len<<<1,128,0,stream>>>(x, len);
  k_init<<<(B_*H_+255)/256,256,0,stream>>>(hxA, hx1, cstate);
  k_zero<<<(FA_WORDS_+255)/256,256,0,stream>>>(flagsA, FA_WORDS_);
  k_zero<<<(FC_WORDS_+255)/256,256,0,stream>>>(flagsC, FC_WORDS_);
  k_fold<<<4,256,0,stream>>>(fc1w, fc1b, fcw, fcb, Mf, bf);

  // ---- phase A: layer-0 fwd+rev, single persistent launch ----
  k_phaseA<<<dim3(2,32,2), 256, 0, stream>>>(
      x, w0fp, w0rp, whf, whr, bs0, len, hxA, outcat, flagsA);

  // ---- phase C: per chunk, dense Z1 GEMM then recurrence ----
  for (int cc = 0; cc < NC; ++cc){
    int t0 = S_ - (cc+1)*CH;     // chunk covers t in [t0, t0+CH), consumed descending
    k_gemm_bt<<<dim3(CH*2,32), 256, 0, stream>>>(
        outcat + (size_t)t0*B_*D1_, w1i, Z1c, bs1r, CH*B_, G_, D1_);
    k_phaseCrec<<<dim3(2,32), 256, 0, stream>>>(
        Z1c, w1h, len, hx1, cstate, h1f, flagsC, cc*CH, CH);
  }

  k_final<<<1,256,0,stream>>>(h1f, Mf, bf, out);
}